// Round 13
// baseline (2639.053 us; speedup 1.0000x reference)
//
#include <hip/hip_runtime.h>

#define B_ 8
#define N_ 8192
#define S_ 1024
#define NS_ 64

typedef float v2f __attribute__((ext_vector_type(2)));
typedef unsigned long long u64;

// out layout (floats)
#define OUT0 0                 // new_xyz (B,3,1024)
#define OUT1 24576             // new_points (B,128,1024)
#define OUT2 1073152           // new_seed (B,1024); fps int-bits until worker converts

// ---------------------------------------------------------------------------
// DPP 64-lane reductions (row_shr 1/2/4/8, row_bcast 15/31; result lane 63).
// HW-validated on gfx950 in rounds 6-12.
// ---------------------------------------------------------------------------
template <int CTRL>
static __device__ __forceinline__ float dpp_max_step(float v) {
    int o = __builtin_amdgcn_update_dpp(__float_as_int(v), __float_as_int(v),
                                        CTRL, 0xf, 0xf, false);
    return fmaxf(v, __int_as_float(o));
}
static __device__ __forceinline__ float wave_max_to_lane63(float v) {
    v = dpp_max_step<0x111>(v);
    v = dpp_max_step<0x112>(v);
    v = dpp_max_step<0x114>(v);
    v = dpp_max_step<0x118>(v);
    v = dpp_max_step<0x142>(v);
    v = dpp_max_step<0x143>(v);
    return v;
}
static __device__ __forceinline__ float wave_max_f32(float v) {
    v = wave_max_to_lane63(v);
    return __int_as_float(__builtin_amdgcn_readlane(__float_as_int(v), 63));
}
template <int CTRL>
static __device__ __forceinline__ unsigned dpp_umin_step(unsigned v) {
    unsigned o = (unsigned)__builtin_amdgcn_update_dpp((int)v, (int)v,
                                                       CTRL, 0xf, 0xf, false);
    return v < o ? v : o;
}
static __device__ __forceinline__ unsigned wave_min_u32(unsigned v) {
    v = dpp_umin_step<0x111>(v);
    v = dpp_umin_step<0x112>(v);
    v = dpp_umin_step<0x114>(v);
    v = dpp_umin_step<0x118>(v);
    v = dpp_umin_step<0x142>(v);
    v = dpp_umin_step<0x143>(v);
    return (unsigned)__builtin_amdgcn_readlane((int)v, 63);
}

#define FPS_T 512
#define FPS_J 8

// ---------------------------------------------------------------------------
// FUSED producer/consumer kernel. Grid = 256 blocks x 512 threads (all
// co-resident on 256 CUs; producers never wait on consumers => deadlock-free).
// Blocks 0..7: exact R11 fps (1078 us proven) + coord stores to OUT0 + a
// release flag every 64 steps. Blocks 8..255: grid-stride workers — acquire
// flag, ballquery (wave 0, gi in LDS), seed conversion, 8-wave ILP mlp.
// ---------------------------------------------------------------------------
__global__ __launch_bounds__(512, 1) void fused_kernel(
    const float* __restrict__ xyz, const float* __restrict__ pts,
    const int* __restrict__ seed,
    const float* __restrict__ w0, const float* __restrict__ b0,
    const float* __restrict__ g0, const float* __restrict__ be0,
    const float* __restrict__ m0, const float* __restrict__ v0,
    const float* __restrict__ w1, const float* __restrict__ b1,
    const float* __restrict__ g1, const float* __restrict__ be1,
    const float* __restrict__ m1, const float* __restrict__ v1,
    const float* __restrict__ w2, const float* __restrict__ b2,
    const float* __restrict__ g2, const float* __restrict__ be2,
    const float* __restrict__ m2, const float* __restrict__ v2,
    float* out, int* flags) {

    __shared__ u64 pairs[2];
    __shared__ float f0[64 * 9];
    __shared__ float bufA[64 * 65];
    __shared__ float bufB[64 * 65];
    __shared__ float scs[256], ofs[256];
    __shared__ int gis[64];

    const int t = threadIdx.x;
    const int lane = t & 63;

    if (blockIdx.x < 8) {
        // ================= producer: fps =================
        const int b = blockIdx.x;
        const float* X = xyz + b * 3 * N_;

        v2f px2[FPS_J], py2[FPS_J], pz2[FPS_J], dist2[FPS_J];
#pragma unroll
        for (int j = 0; j < FPS_J; ++j) {
            int n = t + 1024 * j;
            px2[j] = (v2f){X[n], X[n + 512]};
            py2[j] = (v2f){X[N_ + n], X[N_ + n + 512]};
            pz2[j] = (v2f){X[2 * N_ + n], X[2 * N_ + n + 512]};
            dist2[j] = (v2f){1e10f, 1e10f};
        }

        if (t == 0) { pairs[0] = 0ull; pairs[1] = 0ull; }
        __syncthreads();

        float* oseed = out + OUT2 + b * S_;

        int ci = 0;
        float c0 = X[0], c1 = X[N_], c2 = X[2 * N_];

        for (int step = 0; step < S_; ++step) {
            if (t == 0) oseed[step] = __int_as_float(ci);
            if (t < 3) {
                float cv = (t == 0) ? c0 : (t == 1) ? c1 : c2;
                out[OUT0 + (b * 3 + t) * S_ + step] = cv;
            }

            v2f mv = (v2f){-1.0f, -1.0f};
            {
#pragma clang fp contract(off)
                v2f c0v = (v2f){c0, c0};
                v2f c1v = (v2f){c1, c1};
                v2f c2v = (v2f){c2, c2};
#pragma unroll
                for (int j = 0; j < FPS_J; ++j) {
                    v2f e0 = px2[j] - c0v;
                    v2f e1 = py2[j] - c1v;
                    v2f e2 = pz2[j] - c2v;
                    v2f q0 = e0 * e0;
                    v2f q1 = e1 * e1;
                    v2f q2 = e2 * e2;
                    v2f d  = (q0 + q1) + q2;
                    v2f dm = __builtin_elementwise_min(dist2[j], d);
                    dist2[j] = dm;
                    mv = __builtin_elementwise_max(mv, dm);
                }
            }
            float m = fmaxf(mv.x, mv.y);
            float wmax = wave_max_f32(m);

            unsigned mask = 0u;
#pragma unroll
            for (int j = 0; j < FPS_J; ++j) {
                if (dist2[j].x == wmax) mask |= (1u << (2 * j));
                if (dist2[j].y == wmax) mask |= (1u << (2 * j + 1));
            }
            unsigned cand = 0xffffffffu;
            if (mask) {
                int bit = __ffs(mask) - 1;
                cand = (unsigned)(t + (bit << 9));
            }
            unsigned widx = wave_min_u32(cand);

            if (lane == 0) {
                u64 pv = ((u64)(step + 1) << 45) |
                         ((u64)__float_as_uint(wmax) << 13) |
                         (u64)(8191u - widx);
                atomicMax(&pairs[(step + 1) & 1], pv);
            }
            __syncthreads();

            u64 p = pairs[(step + 1) & 1];
            ci = 8191 - (int)(p & 0x1fffull);
            int cu = __builtin_amdgcn_readfirstlane(ci);
            c0 = X[cu];
            c1 = X[N_ + cu];
            c2 = X[2 * N_ + cu];

            if ((step & 63) == 63 && t == 0) {
                __hip_atomic_store(&flags[b], step + 1, __ATOMIC_RELEASE,
                                   __HIP_MEMORY_SCOPE_AGENT);
            }
        }
    } else {
        // ================= consumer: ballquery + seed + mlp =================
        const int wq = __builtin_amdgcn_readfirstlane(t >> 6);   // 0..7

        // per-channel BN fold, once per block
        if (t < 256) {
            float sc, of;
            if (t < 64) {
                int c = t;
                sc = g0[c] / sqrtf(v0[c] + 1e-5f);
                of = (b0[c] - m0[c]) * sc + be0[c];
            } else if (t < 128) {
                int c = t - 64;
                sc = g1[c] / sqrtf(v1[c] + 1e-5f);
                of = (b1[c] - m1[c]) * sc + be1[c];
            } else {
                int c = t - 128;
                sc = g2[c] / sqrtf(v2[c] + 1e-5f);
                of = (b2[c] - m2[c]) * sc + be2[c];
            }
            scs[t] = sc;
            ofs[t] = of;
        }
        __syncthreads();

        for (int sg = (int)blockIdx.x - 8; sg < B_ * S_; sg += 248) {
            const int b = sg >> 10, s = sg & 1023;
            const int want = s + 1;

            // acquire wait (poison 0xAAAAAAAA is negative -> spins correctly)
            while (__hip_atomic_load(&flags[b], __ATOMIC_ACQUIRE,
                                     __HIP_MEMORY_SCOPE_AGENT) < want) {
                __builtin_amdgcn_s_sleep(8);
            }
            __syncthreads();

            const float* X = xyz + b * 3 * N_;
            float cx = out[OUT0 + (b * 3 + 0) * S_ + s];
            float cy = out[OUT0 + (b * 3 + 1) * S_ + s];
            float cz = out[OUT0 + (b * 3 + 2) * S_ + s];

            if (t < 64) {
                // ballquery by wave 0 -> gis[] in LDS
                int cnt = 0, first = 0;
                for (int base = 0; base < N_ && cnt < NS_; base += 128) {
                    int n0 = base + lane;
                    int n1 = base + 64 + lane;
                    float x0 = X[n0], y0 = X[N_ + n0], z0 = X[2 * N_ + n0];
                    float x1 = X[n1], y1 = X[N_ + n1], z1 = X[2 * N_ + n1];
                    float e0 = x0 - cx, e1 = y0 - cy, e2 = z0 - cz;
                    float d0 = fmaf(e2, e2, fmaf(e1, e1, e0 * e0));
                    float q0 = x1 - cx, q1 = y1 - cy, q2 = z1 - cz;
                    float d1 = fmaf(q2, q2, fmaf(q1, q1, q0 * q0));

                    u64 m0b = __ballot(d0 <= 0.04f);
                    if (m0b) {
                        if (cnt == 0) first = base + __ffsll(m0b) - 1;
                        int pos = cnt + (int)__popcll(m0b & ((1ull << lane) - 1ull));
                        if ((d0 <= 0.04f) && pos < NS_) gis[pos] = n0;
                        cnt += (int)__popcll(m0b);
                    }
                    u64 m1b = __ballot(d1 <= 0.04f);
                    if (m1b) {
                        if (cnt == 0) first = base + 64 + __ffsll(m1b) - 1;
                        int pos = cnt + (int)__popcll(m1b & ((1ull << lane) - 1ull));
                        if ((d1 <= 0.04f) && pos < NS_) gis[pos] = n1;
                        cnt += (int)__popcll(m1b);
                    }
                }
                if (lane >= cnt && lane < NS_) gis[lane] = first;
            } else if (t == 64) {
                // seed conversion (fps wrote int-bits; overwrite with value)
                int sidx = __float_as_int(out[OUT2 + b * S_ + s]) & 8191;
                out[OUT2 + b * S_ + s] = (float)seed[b * N_ + sidx];
            }
            __syncthreads();

            if (t < 64) {
                int gidx = gis[t] & 8191;
                const float* P = pts + b * 3 * N_;
                f0[t * 9 + 0] = X[gidx] - cx;
                f0[t * 9 + 1] = X[N_ + gidx] - cy;
                f0[t * 9 + 2] = X[2 * N_ + gidx] - cz;
                f0[t * 9 + 3] = P[gidx];
                f0[t * 9 + 4] = P[N_ + gidx];
                f0[t * 9 + 5] = P[2 * N_ + gidx];
            }
            __syncthreads();

            // layer 0: 6 -> 64 (8 waves, o-slice of 8 each, 4 chains)
            {
                float in[6];
#pragma unroll
                for (int c = 0; c < 6; ++c) in[c] = f0[lane * 9 + c];
#pragma unroll 1
                for (int i = 0; i < 8; i += 4) {
                    int o = wq * 8 + i;
                    float a0 = 0.f, a1 = 0.f, a2 = 0.f, a3 = 0.f;
#pragma unroll
                    for (int c = 0; c < 6; ++c) {
                        float rc = in[c];
                        a0 = fmaf(rc, w0[(o + 0) * 6 + c], a0);
                        a1 = fmaf(rc, w0[(o + 1) * 6 + c], a1);
                        a2 = fmaf(rc, w0[(o + 2) * 6 + c], a2);
                        a3 = fmaf(rc, w0[(o + 3) * 6 + c], a3);
                    }
                    bufA[lane * 65 + o + 0] = fmaxf(fmaf(a0, scs[o + 0], ofs[o + 0]), 0.f);
                    bufA[lane * 65 + o + 1] = fmaxf(fmaf(a1, scs[o + 1], ofs[o + 1]), 0.f);
                    bufA[lane * 65 + o + 2] = fmaxf(fmaf(a2, scs[o + 2], ofs[o + 2]), 0.f);
                    bufA[lane * 65 + o + 3] = fmaxf(fmaf(a3, scs[o + 3], ofs[o + 3]), 0.f);
                }
            }
            __syncthreads();

            // layer 1: 64 -> 64
            {
                float r[64];
#pragma unroll
                for (int c = 0; c < 64; ++c) r[c] = bufA[lane * 65 + c];
#pragma unroll 1
                for (int i = 0; i < 8; i += 4) {
                    int o = wq * 8 + i;
                    float a0 = 0.f, a1 = 0.f, a2 = 0.f, a3 = 0.f;
#pragma unroll
                    for (int c = 0; c < 64; ++c) {
                        float rc = r[c];
                        a0 = fmaf(rc, w1[(o + 0) * 64 + c], a0);
                        a1 = fmaf(rc, w1[(o + 1) * 64 + c], a1);
                        a2 = fmaf(rc, w1[(o + 2) * 64 + c], a2);
                        a3 = fmaf(rc, w1[(o + 3) * 64 + c], a3);
                    }
                    bufB[lane * 65 + o + 0] = fmaxf(fmaf(a0, scs[64 + o + 0], ofs[64 + o + 0]), 0.f);
                    bufB[lane * 65 + o + 1] = fmaxf(fmaf(a1, scs[64 + o + 1], ofs[64 + o + 1]), 0.f);
                    bufB[lane * 65 + o + 2] = fmaxf(fmaf(a2, scs[64 + o + 2], ofs[64 + o + 2]), 0.f);
                    bufB[lane * 65 + o + 3] = fmaxf(fmaf(a3, scs[64 + o + 3], ofs[64 + o + 3]), 0.f);
                }
            }
            __syncthreads();

            // layer 2: 64 -> 128, fused max over k (DPP), lane 63 stores
            {
                float r[64];
#pragma unroll
                for (int c = 0; c < 64; ++c) r[c] = bufB[lane * 65 + c];
#pragma unroll 1
                for (int i = 0; i < 16; i += 4) {
                    int o = wq * 16 + i;
                    float a0 = 0.f, a1 = 0.f, a2 = 0.f, a3 = 0.f;
#pragma unroll
                    for (int c = 0; c < 64; ++c) {
                        float rc = r[c];
                        a0 = fmaf(rc, w2[(o + 0) * 64 + c], a0);
                        a1 = fmaf(rc, w2[(o + 1) * 64 + c], a1);
                        a2 = fmaf(rc, w2[(o + 2) * 64 + c], a2);
                        a3 = fmaf(rc, w2[(o + 3) * 64 + c], a3);
                    }
                    float y0 = wave_max_to_lane63(fmaxf(fmaf(a0, scs[128 + o + 0], ofs[128 + o + 0]), 0.f));
                    float y1 = wave_max_to_lane63(fmaxf(fmaf(a1, scs[128 + o + 1], ofs[128 + o + 1]), 0.f));
                    float y2 = wave_max_to_lane63(fmaxf(fmaf(a2, scs[128 + o + 2], ofs[128 + o + 2]), 0.f));
                    float y3 = wave_max_to_lane63(fmaxf(fmaf(a3, scs[128 + o + 3], ofs[128 + o + 3]), 0.f));
                    if (lane == 63) {
                        out[OUT1 + (b * 128 + o + 0) * S_ + s] = y0;
                        out[OUT1 + (b * 128 + o + 1) * S_ + s] = y1;
                        out[OUT1 + (b * 128 + o + 2) * S_ + s] = y2;
                        out[OUT1 + (b * 128 + o + 3) * S_ + s] = y3;
                    }
                }
            }
            __syncthreads();   // LDS reuse fence before next centroid
        }
    }
}

// ============================================================================
// Fallback sequential path (proven R12 kernels) — used only if ws_size < 64.
// ============================================================================
__global__ __launch_bounds__(FPS_T, 1) void fps_kernel(const float* __restrict__ xyz,
                                                       float* out) {
    const int b = blockIdx.x;
    const int t = threadIdx.x;
    const int lane = t & 63;
    const float* X = xyz + b * 3 * N_;

    v2f px2[FPS_J], py2[FPS_J], pz2[FPS_J], dist2[FPS_J];
#pragma unroll
    for (int j = 0; j < FPS_J; ++j) {
        int n = t + 1024 * j;
        px2[j] = (v2f){X[n], X[n + 512]};
        py2[j] = (v2f){X[N_ + n], X[N_ + n + 512]};
        pz2[j] = (v2f){X[2 * N_ + n], X[2 * N_ + n + 512]};
        dist2[j] = (v2f){1e10f, 1e10f};
    }
    __shared__ u64 pairs[2];
    if (t == 0) { pairs[0] = 0ull; pairs[1] = 0ull; }
    __syncthreads();
    float* oseed = out + OUT2 + b * S_;
    int ci = 0;
    float c0 = X[0], c1 = X[N_], c2 = X[2 * N_];
    for (int step = 0; step < S_; ++step) {
        if (t == 0) oseed[step] = __int_as_float(ci);
        if (t < 3) {
            float cv = (t == 0) ? c0 : (t == 1) ? c1 : c2;
            out[OUT0 + (b * 3 + t) * S_ + step] = cv;
        }
        v2f mv = (v2f){-1.0f, -1.0f};
        {
#pragma clang fp contract(off)
            v2f c0v = (v2f){c0, c0};
            v2f c1v = (v2f){c1, c1};
            v2f c2v = (v2f){c2, c2};
#pragma unroll
            for (int j = 0; j < FPS_J; ++j) {
                v2f e0 = px2[j] - c0v;
                v2f e1 = py2[j] - c1v;
                v2f e2 = pz2[j] - c2v;
                v2f q0 = e0 * e0;
                v2f q1 = e1 * e1;
                v2f q2 = e2 * e2;
                v2f d  = (q0 + q1) + q2;
                v2f dm = __builtin_elementwise_min(dist2[j], d);
                dist2[j] = dm;
                mv = __builtin_elementwise_max(mv, dm);
            }
        }
        float m = fmaxf(mv.x, mv.y);
        float wmax = wave_max_f32(m);
        unsigned mask = 0u;
#pragma unroll
        for (int j = 0; j < FPS_J; ++j) {
            if (dist2[j].x == wmax) mask |= (1u << (2 * j));
            if (dist2[j].y == wmax) mask |= (1u << (2 * j + 1));
        }
        unsigned cand = 0xffffffffu;
        if (mask) {
            int bit = __ffs(mask) - 1;
            cand = (unsigned)(t + (bit << 9));
        }
        unsigned widx = wave_min_u32(cand);
        if (lane == 0) {
            u64 pv = ((u64)(step + 1) << 45) |
                     ((u64)__float_as_uint(wmax) << 13) |
                     (u64)(8191u - widx);
            atomicMax(&pairs[(step + 1) & 1], pv);
        }
        __syncthreads();
        u64 p = pairs[(step + 1) & 1];
        ci = 8191 - (int)(p & 0x1fffull);
        int cu = __builtin_amdgcn_readfirstlane(ci);
        c0 = X[cu];
        c1 = X[N_ + cu];
        c2 = X[2 * N_ + cu];
    }
}

__global__ __launch_bounds__(256) void seedconv_kernel(const int* __restrict__ seed,
                                                       float* out) {
    int t = blockIdx.x * 256 + threadIdx.x;   // 8192
    int b = t >> 10;
    int idx = __float_as_int(out[OUT2 + t]) & 8191;
    out[OUT2 + t] = (float)seed[b * N_ + idx];
}

__global__ __launch_bounds__(256) void ballquery_kernel(const float* __restrict__ xyz,
                                                        float* out) {
    int wid = threadIdx.x >> 6, lane = threadIdx.x & 63;
    int sg = blockIdx.x * 4 + wid;
    int b = sg >> 10, s = sg & 1023;
    const float* X = xyz + b * 3 * N_;
    float c0 = out[OUT0 + (b * 3 + 0) * S_ + s];
    float c1 = out[OUT0 + (b * 3 + 1) * S_ + s];
    float c2 = out[OUT0 + (b * 3 + 2) * S_ + s];
    float* G = out + OUT1 + (b * 128) * S_ + s;
    int cnt = 0, first = 0;
    for (int base = 0; base < N_ && cnt < NS_; base += 128) {
        int n0 = base + lane;
        int n1 = base + 64 + lane;
        float x0 = X[n0], y0 = X[N_ + n0], z0 = X[2 * N_ + n0];
        float x1 = X[n1], y1 = X[N_ + n1], z1 = X[2 * N_ + n1];
        float e0 = x0 - c0, e1 = y0 - c1, e2 = z0 - c2;
        float d0 = fmaf(e2, e2, fmaf(e1, e1, e0 * e0));
        float q0 = x1 - c0, q1 = y1 - c1, q2 = z1 - c2;
        float d1 = fmaf(q2, q2, fmaf(q1, q1, q0 * q0));
        u64 m0b = __ballot(d0 <= 0.04f);
        if (m0b) {
            if (cnt == 0) first = base + __ffsll(m0b) - 1;
            int pos = cnt + (int)__popcll(m0b & ((1ull << lane) - 1ull));
            if ((d0 <= 0.04f) && pos < NS_) G[pos * S_] = __int_as_float(n0);
            cnt += (int)__popcll(m0b);
        }
        u64 m1b = __ballot(d1 <= 0.04f);
        if (m1b) {
            if (cnt == 0) first = base + 64 + __ffsll(m1b) - 1;
            int pos = cnt + (int)__popcll(m1b & ((1ull << lane) - 1ull));
            if ((d1 <= 0.04f) && pos < NS_) G[pos * S_] = __int_as_float(n1);
            cnt += (int)__popcll(m1b);
        }
    }
    if (lane >= cnt && lane < NS_) G[lane * S_] = __int_as_float(first);
}

__global__ __launch_bounds__(256) void mlp_kernel(
    const float* __restrict__ xyz, const float* __restrict__ pts,
    const float* __restrict__ w0, const float* __restrict__ b0,
    const float* __restrict__ g0, const float* __restrict__ be0,
    const float* __restrict__ m0, const float* __restrict__ v0,
    const float* __restrict__ w1, const float* __restrict__ b1,
    const float* __restrict__ g1, const float* __restrict__ be1,
    const float* __restrict__ m1, const float* __restrict__ v1,
    const float* __restrict__ w2, const float* __restrict__ b2,
    const float* __restrict__ g2, const float* __restrict__ be2,
    const float* __restrict__ m2, const float* __restrict__ v2,
    float* out) {
    const int sg = blockIdx.x;
    const int b = sg >> 10, s = sg & 1023;
    const int t = threadIdx.x;
    const int lane = t & 63;
    const int wq = __builtin_amdgcn_readfirstlane(t >> 6);

    __shared__ float f0[64 * 9];
    __shared__ float bufA[64 * 65];
    __shared__ float bufB[64 * 65];
    __shared__ float scs[256], ofs[256];

    {
        float sc, of;
        if (t < 64) {
            int c = t;
            sc = g0[c] / sqrtf(v0[c] + 1e-5f);
            of = (b0[c] - m0[c]) * sc + be0[c];
        } else if (t < 128) {
            int c = t - 64;
            sc = g1[c] / sqrtf(v1[c] + 1e-5f);
            of = (b1[c] - m1[c]) * sc + be1[c];
        } else {
            int c = t - 128;
            sc = g2[c] / sqrtf(v2[c] + 1e-5f);
            of = (b2[c] - m2[c]) * sc + be2[c];
        }
        scs[t] = sc;
        ofs[t] = of;
    }

    if (t < 64) {
        int gidx = __float_as_int(out[OUT1 + (b * 128 + t) * S_ + s]) & 8191;
        const float* X = xyz + b * 3 * N_;
        const float* P = pts + b * 3 * N_;
        float cx = out[OUT0 + (b * 3 + 0) * S_ + s];
        float cy = out[OUT0 + (b * 3 + 1) * S_ + s];
        float cz = out[OUT0 + (b * 3 + 2) * S_ + s];
        f0[t * 9 + 0] = X[gidx] - cx;
        f0[t * 9 + 1] = X[N_ + gidx] - cy;
        f0[t * 9 + 2] = X[2 * N_ + gidx] - cz;
        f0[t * 9 + 3] = P[gidx];
        f0[t * 9 + 4] = P[N_ + gidx];
        f0[t * 9 + 5] = P[2 * N_ + gidx];
    }
    __syncthreads();

    {
        float in[6];
#pragma unroll
        for (int c = 0; c < 6; ++c) in[c] = f0[lane * 9 + c];
#pragma unroll 1
        for (int i = 0; i < 16; i += 4) {
            int o = wq * 16 + i;
            float a0 = 0.f, a1 = 0.f, a2 = 0.f, a3 = 0.f;
#pragma unroll
            for (int c = 0; c < 6; ++c) {
                float rc = in[c];
                a0 = fmaf(rc, w0[(o + 0) * 6 + c], a0);
                a1 = fmaf(rc, w0[(o + 1) * 6 + c], a1);
                a2 = fmaf(rc, w0[(o + 2) * 6 + c], a2);
                a3 = fmaf(rc, w0[(o + 3) * 6 + c], a3);
            }
            bufA[lane * 65 + o + 0] = fmaxf(fmaf(a0, scs[o + 0], ofs[o + 0]), 0.f);
            bufA[lane * 65 + o + 1] = fmaxf(fmaf(a1, scs[o + 1], ofs[o + 1]), 0.f);
            bufA[lane * 65 + o + 2] = fmaxf(fmaf(a2, scs[o + 2], ofs[o + 2]), 0.f);
            bufA[lane * 65 + o + 3] = fmaxf(fmaf(a3, scs[o + 3], ofs[o + 3]), 0.f);
        }
    }
    __syncthreads();

    {
        float r[64];
#pragma unroll
        for (int c = 0; c < 64; ++c) r[c] = bufA[lane * 65 + c];
#pragma unroll 1
        for (int i = 0; i < 16; i += 4) {
            int o = wq * 16 + i;
            float a0 = 0.f, a1 = 0.f, a2 = 0.f, a3 = 0.f;
#pragma unroll
            for (int c = 0; c < 64; ++c) {
                float rc = r[c];
                a0 = fmaf(rc, w1[(o + 0) * 64 + c], a0);
                a1 = fmaf(rc, w1[(o + 1) * 64 + c], a1);
                a2 = fmaf(rc, w1[(o + 2) * 64 + c], a2);
                a3 = fmaf(rc, w1[(o + 3) * 64 + c], a3);
            }
            bufB[lane * 65 + o + 0] = fmaxf(fmaf(a0, scs[64 + o + 0], ofs[64 + o + 0]), 0.f);
            bufB[lane * 65 + o + 1] = fmaxf(fmaf(a1, scs[64 + o + 1], ofs[64 + o + 1]), 0.f);
            bufB[lane * 65 + o + 2] = fmaxf(fmaf(a2, scs[64 + o + 2], ofs[64 + o + 2]), 0.f);
            bufB[lane * 65 + o + 3] = fmaxf(fmaf(a3, scs[64 + o + 3], ofs[64 + o + 3]), 0.f);
        }
    }
    __syncthreads();

    {
        float r[64];
#pragma unroll
        for (int c = 0; c < 64; ++c) r[c] = bufB[lane * 65 + c];
#pragma unroll 1
        for (int i = 0; i < 32; i += 4) {
            int o = wq * 32 + i;
            float a0 = 0.f, a1 = 0.f, a2 = 0.f, a3 = 0.f;
#pragma unroll
            for (int c = 0; c < 64; ++c) {
                float rc = r[c];
                a0 = fmaf(rc, w2[(o + 0) * 64 + c], a0);
                a1 = fmaf(rc, w2[(o + 1) * 64 + c], a1);
                a2 = fmaf(rc, w2[(o + 2) * 64 + c], a2);
                a3 = fmaf(rc, w2[(o + 3) * 64 + c], a3);
            }
            float y0 = wave_max_to_lane63(fmaxf(fmaf(a0, scs[128 + o + 0], ofs[128 + o + 0]), 0.f));
            float y1 = wave_max_to_lane63(fmaxf(fmaf(a1, scs[128 + o + 1], ofs[128 + o + 1]), 0.f));
            float y2 = wave_max_to_lane63(fmaxf(fmaf(a2, scs[128 + o + 2], ofs[128 + o + 2]), 0.f));
            float y3 = wave_max_to_lane63(fmaxf(fmaf(a3, scs[128 + o + 3], ofs[128 + o + 3]), 0.f));
            if (lane == 63) {
                out[OUT1 + (b * 128 + o + 0) * S_ + s] = y0;
                out[OUT1 + (b * 128 + o + 1) * S_ + s] = y1;
                out[OUT1 + (b * 128 + o + 2) * S_ + s] = y2;
                out[OUT1 + (b * 128 + o + 3) * S_ + s] = y3;
            }
        }
    }
}

extern "C" void kernel_launch(void* const* d_in, const int* in_sizes, int n_in,
                              void* d_out, int out_size, void* d_ws, size_t ws_size,
                              hipStream_t stream) {
    const float* xyz  = (const float*)d_in[0];
    const float* pts  = (const float*)d_in[1];
    const int*   seed = (const int*)d_in[2];
    const float* w0 = (const float*)d_in[3];
    const float* b0 = (const float*)d_in[4];
    const float* g0 = (const float*)d_in[5];
    const float* be0 = (const float*)d_in[6];
    const float* m0 = (const float*)d_in[7];
    const float* v0 = (const float*)d_in[8];
    const float* w1 = (const float*)d_in[9];
    const float* b1 = (const float*)d_in[10];
    const float* g1 = (const float*)d_in[11];
    const float* be1 = (const float*)d_in[12];
    const float* m1 = (const float*)d_in[13];
    const float* v1 = (const float*)d_in[14];
    const float* w2 = (const float*)d_in[15];
    const float* b2 = (const float*)d_in[16];
    const float* g2 = (const float*)d_in[17];
    const float* be2 = (const float*)d_in[18];
    const float* m2 = (const float*)d_in[19];
    const float* v2 = (const float*)d_in[20];
    float* out = (float*)d_out;

    if (ws_size >= 64) {
        int* flags = (int*)d_ws;
        hipMemsetAsync(flags, 0, 64, stream);
        fused_kernel<<<dim3(256), dim3(512), 0, stream>>>(xyz, pts, seed,
            w0, b0, g0, be0, m0, v0,
            w1, b1, g1, be1, m1, v1,
            w2, b2, g2, be2, m2, v2,
            out, flags);
    } else {
        fps_kernel<<<dim3(B_), dim3(FPS_T), 0, stream>>>(xyz, out);
        seedconv_kernel<<<dim3(8192 / 256), dim3(256), 0, stream>>>(seed, out);
        // stage gi in OUT1 then mlp (legacy path)
        ballquery_kernel<<<dim3(2048), dim3(256), 0, stream>>>(xyz, out);
        mlp_kernel<<<dim3(8192), dim3(256), 0, stream>>>(xyz, pts,
            w0, b0, g0, be0, m0, v0,
            w1, b1, g1, be1, m1, v1,
            w2, b2, g2, be2, m2, v2,
            out);
    }
}

// Round 14
// 2283.205 us; speedup vs baseline: 1.1559x; 1.1559x over previous
//
#include <hip/hip_runtime.h>

#define B_ 8
#define N_ 8192
#define S_ 1024
#define NS_ 64

typedef float v2f __attribute__((ext_vector_type(2)));
typedef unsigned long long u64;

// out layout (floats)
#define OUT0 0                 // new_xyz (B,3,1024)
#define OUT1 24576             // new_points (B,128,1024)
#define OUT2 1073152           // new_seed (B,1024); fps int-bits until worker converts

// ---------------------------------------------------------------------------
// DPP 64-lane reductions (row_shr 1/2/4/8, row_bcast 15/31; result lane 63).
// HW-validated on gfx950 in rounds 6-13.
// ---------------------------------------------------------------------------
template <int CTRL>
static __device__ __forceinline__ float dpp_max_step(float v) {
    int o = __builtin_amdgcn_update_dpp(__float_as_int(v), __float_as_int(v),
                                        CTRL, 0xf, 0xf, false);
    return fmaxf(v, __int_as_float(o));
}
static __device__ __forceinline__ float wave_max_to_lane63(float v) {
    v = dpp_max_step<0x111>(v);
    v = dpp_max_step<0x112>(v);
    v = dpp_max_step<0x114>(v);
    v = dpp_max_step<0x118>(v);
    v = dpp_max_step<0x142>(v);
    v = dpp_max_step<0x143>(v);
    return v;
}
static __device__ __forceinline__ float wave_max_f32(float v) {
    v = wave_max_to_lane63(v);
    return __int_as_float(__builtin_amdgcn_readlane(__float_as_int(v), 63));
}
template <int CTRL>
static __device__ __forceinline__ unsigned dpp_umin_step(unsigned v) {
    unsigned o = (unsigned)__builtin_amdgcn_update_dpp((int)v, (int)v,
                                                       CTRL, 0xf, 0xf, false);
    return v < o ? v : o;
}
static __device__ __forceinline__ unsigned wave_min_u32(unsigned v) {
    v = dpp_umin_step<0x111>(v);
    v = dpp_umin_step<0x112>(v);
    v = dpp_umin_step<0x114>(v);
    v = dpp_umin_step<0x118>(v);
    v = dpp_umin_step<0x142>(v);
    v = dpp_umin_step<0x143>(v);
    return (unsigned)__builtin_amdgcn_readlane((int)v, 63);
}

#define FPS_T 512
#define FPS_J 8

// ---------------------------------------------------------------------------
// FUSED producer/consumer kernel. Grid = 256 blocks x 512 threads.
// LDS padded >81920 B => HARD 1 block/CU (R13 regression root cause #1:
// 2 blocks/CU packing let worker blocks steal producer CU issue slots).
// Spin: only t==0, cacheline-padded flags, s_sleep backoff (root cause #2:
// 512-thread AGENT-acquire spin storms the fabric).
// Blocks 0..7: exact R11 fps + coord stores + release flag every 64 steps.
// Blocks 8..255: grid-stride workers — t0 acquire-spin, ballquery (wave 0,
// gi in LDS), seed conversion, 8-wave ILP mlp.
// ---------------------------------------------------------------------------
__global__ __launch_bounds__(512, 1) void fused_kernel(
    const float* __restrict__ xyz, const float* __restrict__ pts,
    const int* __restrict__ seed,
    const float* __restrict__ w0, const float* __restrict__ b0,
    const float* __restrict__ g0, const float* __restrict__ be0,
    const float* __restrict__ m0, const float* __restrict__ v0,
    const float* __restrict__ w1, const float* __restrict__ b1,
    const float* __restrict__ g1, const float* __restrict__ be1,
    const float* __restrict__ m1, const float* __restrict__ v1,
    const float* __restrict__ w2, const float* __restrict__ b2,
    const float* __restrict__ g2, const float* __restrict__ be2,
    const float* __restrict__ m2, const float* __restrict__ v2,
    float* out, int* flags) {

    __shared__ u64 pairs[2];
    __shared__ float f0[64 * 9];
    __shared__ float bufA[64 * 65];
    __shared__ float bufB[64 * 65];
    __shared__ float scs[256], ofs[256];
    __shared__ int gis[64];
    __shared__ volatile float pad_lds[11008];   // occupancy limiter: 1 block/CU

    const int t = threadIdx.x;
    const int lane = t & 63;
    if (t == 0) pad_lds[0] = 0.f;   // keep allocation alive

    if (blockIdx.x < 8) {
        // ================= producer: fps =================
        const int b = blockIdx.x;
        const float* X = xyz + b * 3 * N_;

        v2f px2[FPS_J], py2[FPS_J], pz2[FPS_J], dist2[FPS_J];
#pragma unroll
        for (int j = 0; j < FPS_J; ++j) {
            int n = t + 1024 * j;
            px2[j] = (v2f){X[n], X[n + 512]};
            py2[j] = (v2f){X[N_ + n], X[N_ + n + 512]};
            pz2[j] = (v2f){X[2 * N_ + n], X[2 * N_ + n + 512]};
            dist2[j] = (v2f){1e10f, 1e10f};
        }

        if (t == 0) { pairs[0] = 0ull; pairs[1] = 0ull; }
        __syncthreads();

        float* oseed = out + OUT2 + b * S_;

        int ci = 0;
        float c0 = X[0], c1 = X[N_], c2 = X[2 * N_];

        for (int step = 0; step < S_; ++step) {
            if (t == 0) oseed[step] = __int_as_float(ci);
            if (t < 3) {
                float cv = (t == 0) ? c0 : (t == 1) ? c1 : c2;
                out[OUT0 + (b * 3 + t) * S_ + step] = cv;
            }

            v2f mv = (v2f){-1.0f, -1.0f};
            {
#pragma clang fp contract(off)
                v2f c0v = (v2f){c0, c0};
                v2f c1v = (v2f){c1, c1};
                v2f c2v = (v2f){c2, c2};
#pragma unroll
                for (int j = 0; j < FPS_J; ++j) {
                    v2f e0 = px2[j] - c0v;
                    v2f e1 = py2[j] - c1v;
                    v2f e2 = pz2[j] - c2v;
                    v2f q0 = e0 * e0;
                    v2f q1 = e1 * e1;
                    v2f q2 = e2 * e2;
                    v2f d  = (q0 + q1) + q2;
                    v2f dm = __builtin_elementwise_min(dist2[j], d);
                    dist2[j] = dm;
                    mv = __builtin_elementwise_max(mv, dm);
                }
            }
            float m = fmaxf(mv.x, mv.y);
            float wmax = wave_max_f32(m);

            unsigned mask = 0u;
#pragma unroll
            for (int j = 0; j < FPS_J; ++j) {
                if (dist2[j].x == wmax) mask |= (1u << (2 * j));
                if (dist2[j].y == wmax) mask |= (1u << (2 * j + 1));
            }
            unsigned cand = 0xffffffffu;
            if (mask) {
                int bit = __ffs(mask) - 1;
                cand = (unsigned)(t + (bit << 9));
            }
            unsigned widx = wave_min_u32(cand);

            if (lane == 0) {
                u64 pv = ((u64)(step + 1) << 45) |
                         ((u64)__float_as_uint(wmax) << 13) |
                         (u64)(8191u - widx);
                atomicMax(&pairs[(step + 1) & 1], pv);
            }
            __syncthreads();

            u64 p = pairs[(step + 1) & 1];
            ci = 8191 - (int)(p & 0x1fffull);
            int cu = __builtin_amdgcn_readfirstlane(ci);
            c0 = X[cu];
            c1 = X[N_ + cu];
            c2 = X[2 * N_ + cu];

            if ((step & 63) == 63 && t == 0) {
                __hip_atomic_store(&flags[b << 5], step + 1, __ATOMIC_RELEASE,
                                   __HIP_MEMORY_SCOPE_AGENT);
            }
        }
    } else {
        // ================= consumer: ballquery + seed + mlp =================
        const int wq = __builtin_amdgcn_readfirstlane(t >> 6);   // 0..7

        // per-channel BN fold, once per block
        if (t < 256) {
            float sc, of;
            if (t < 64) {
                int c = t;
                sc = g0[c] / sqrtf(v0[c] + 1e-5f);
                of = (b0[c] - m0[c]) * sc + be0[c];
            } else if (t < 128) {
                int c = t - 64;
                sc = g1[c] / sqrtf(v1[c] + 1e-5f);
                of = (b1[c] - m1[c]) * sc + be1[c];
            } else {
                int c = t - 128;
                sc = g2[c] / sqrtf(v2[c] + 1e-5f);
                of = (b2[c] - m2[c]) * sc + be2[c];
            }
            scs[t] = sc;
            ofs[t] = of;
        }
        __syncthreads();

        for (int sg = (int)blockIdx.x - 8; sg < B_ * S_; sg += 248) {
            const int b = sg >> 10, s = sg & 1023;
            const int want = s + 1;

            // single-thread acquire spin (poison 0xAAAAAAAA < 0 -> spins ok);
            // acquire's L1-invalidate is CU-wide, barrier propagates to block
            if (t == 0) {
                while (__hip_atomic_load(&flags[b << 5], __ATOMIC_ACQUIRE,
                                         __HIP_MEMORY_SCOPE_AGENT) < want) {
                    __builtin_amdgcn_s_sleep(32);
                }
            }
            __syncthreads();

            const float* X = xyz + b * 3 * N_;
            float cx = out[OUT0 + (b * 3 + 0) * S_ + s];
            float cy = out[OUT0 + (b * 3 + 1) * S_ + s];
            float cz = out[OUT0 + (b * 3 + 2) * S_ + s];

            if (t < 64) {
                // ballquery by wave 0 -> gis[] in LDS
                int cnt = 0, first = 0;
                for (int base = 0; base < N_ && cnt < NS_; base += 128) {
                    int n0 = base + lane;
                    int n1 = base + 64 + lane;
                    float x0 = X[n0], y0 = X[N_ + n0], z0 = X[2 * N_ + n0];
                    float x1 = X[n1], y1 = X[N_ + n1], z1 = X[2 * N_ + n1];
                    float e0 = x0 - cx, e1 = y0 - cy, e2 = z0 - cz;
                    float d0 = fmaf(e2, e2, fmaf(e1, e1, e0 * e0));
                    float q0 = x1 - cx, q1 = y1 - cy, q2 = z1 - cz;
                    float d1 = fmaf(q2, q2, fmaf(q1, q1, q0 * q0));

                    u64 m0b = __ballot(d0 <= 0.04f);
                    if (m0b) {
                        if (cnt == 0) first = base + __ffsll(m0b) - 1;
                        int pos = cnt + (int)__popcll(m0b & ((1ull << lane) - 1ull));
                        if ((d0 <= 0.04f) && pos < NS_) gis[pos] = n0;
                        cnt += (int)__popcll(m0b);
                    }
                    u64 m1b = __ballot(d1 <= 0.04f);
                    if (m1b) {
                        if (cnt == 0) first = base + 64 + __ffsll(m1b) - 1;
                        int pos = cnt + (int)__popcll(m1b & ((1ull << lane) - 1ull));
                        if ((d1 <= 0.04f) && pos < NS_) gis[pos] = n1;
                        cnt += (int)__popcll(m1b);
                    }
                }
                if (lane >= cnt && lane < NS_) gis[lane] = first;
            } else if (t == 64) {
                // seed conversion (fps wrote int-bits; overwrite with value)
                int sidx = __float_as_int(out[OUT2 + b * S_ + s]) & 8191;
                out[OUT2 + b * S_ + s] = (float)seed[b * N_ + sidx];
            }
            __syncthreads();

            if (t < 64) {
                int gidx = gis[t] & 8191;
                const float* P = pts + b * 3 * N_;
                f0[t * 9 + 0] = X[gidx] - cx;
                f0[t * 9 + 1] = X[N_ + gidx] - cy;
                f0[t * 9 + 2] = X[2 * N_ + gidx] - cz;
                f0[t * 9 + 3] = P[gidx];
                f0[t * 9 + 4] = P[N_ + gidx];
                f0[t * 9 + 5] = P[2 * N_ + gidx];
            }
            __syncthreads();

            // layer 0: 6 -> 64 (8 waves, o-slice of 8 each, 4 chains)
            {
                float in[6];
#pragma unroll
                for (int c = 0; c < 6; ++c) in[c] = f0[lane * 9 + c];
#pragma unroll 1
                for (int i = 0; i < 8; i += 4) {
                    int o = wq * 8 + i;
                    float a0 = 0.f, a1 = 0.f, a2 = 0.f, a3 = 0.f;
#pragma unroll
                    for (int c = 0; c < 6; ++c) {
                        float rc = in[c];
                        a0 = fmaf(rc, w0[(o + 0) * 6 + c], a0);
                        a1 = fmaf(rc, w0[(o + 1) * 6 + c], a1);
                        a2 = fmaf(rc, w0[(o + 2) * 6 + c], a2);
                        a3 = fmaf(rc, w0[(o + 3) * 6 + c], a3);
                    }
                    bufA[lane * 65 + o + 0] = fmaxf(fmaf(a0, scs[o + 0], ofs[o + 0]), 0.f);
                    bufA[lane * 65 + o + 1] = fmaxf(fmaf(a1, scs[o + 1], ofs[o + 1]), 0.f);
                    bufA[lane * 65 + o + 2] = fmaxf(fmaf(a2, scs[o + 2], ofs[o + 2]), 0.f);
                    bufA[lane * 65 + o + 3] = fmaxf(fmaf(a3, scs[o + 3], ofs[o + 3]), 0.f);
                }
            }
            __syncthreads();

            // layer 1: 64 -> 64
            {
                float r[64];
#pragma unroll
                for (int c = 0; c < 64; ++c) r[c] = bufA[lane * 65 + c];
#pragma unroll 1
                for (int i = 0; i < 8; i += 4) {
                    int o = wq * 8 + i;
                    float a0 = 0.f, a1 = 0.f, a2 = 0.f, a3 = 0.f;
#pragma unroll
                    for (int c = 0; c < 64; ++c) {
                        float rc = r[c];
                        a0 = fmaf(rc, w1[(o + 0) * 64 + c], a0);
                        a1 = fmaf(rc, w1[(o + 1) * 64 + c], a1);
                        a2 = fmaf(rc, w1[(o + 2) * 64 + c], a2);
                        a3 = fmaf(rc, w1[(o + 3) * 64 + c], a3);
                    }
                    bufB[lane * 65 + o + 0] = fmaxf(fmaf(a0, scs[64 + o + 0], ofs[64 + o + 0]), 0.f);
                    bufB[lane * 65 + o + 1] = fmaxf(fmaf(a1, scs[64 + o + 1], ofs[64 + o + 1]), 0.f);
                    bufB[lane * 65 + o + 2] = fmaxf(fmaf(a2, scs[64 + o + 2], ofs[64 + o + 2]), 0.f);
                    bufB[lane * 65 + o + 3] = fmaxf(fmaf(a3, scs[64 + o + 3], ofs[64 + o + 3]), 0.f);
                }
            }
            __syncthreads();

            // layer 2: 64 -> 128, fused max over k (DPP), lane 63 stores
            {
                float r[64];
#pragma unroll
                for (int c = 0; c < 64; ++c) r[c] = bufB[lane * 65 + c];
#pragma unroll 1
                for (int i = 0; i < 16; i += 4) {
                    int o = wq * 16 + i;
                    float a0 = 0.f, a1 = 0.f, a2 = 0.f, a3 = 0.f;
#pragma unroll
                    for (int c = 0; c < 64; ++c) {
                        float rc = r[c];
                        a0 = fmaf(rc, w2[(o + 0) * 64 + c], a0);
                        a1 = fmaf(rc, w2[(o + 1) * 64 + c], a1);
                        a2 = fmaf(rc, w2[(o + 2) * 64 + c], a2);
                        a3 = fmaf(rc, w2[(o + 3) * 64 + c], a3);
                    }
                    float y0 = wave_max_to_lane63(fmaxf(fmaf(a0, scs[128 + o + 0], ofs[128 + o + 0]), 0.f));
                    float y1 = wave_max_to_lane63(fmaxf(fmaf(a1, scs[128 + o + 1], ofs[128 + o + 1]), 0.f));
                    float y2 = wave_max_to_lane63(fmaxf(fmaf(a2, scs[128 + o + 2], ofs[128 + o + 2]), 0.f));
                    float y3 = wave_max_to_lane63(fmaxf(fmaf(a3, scs[128 + o + 3], ofs[128 + o + 3]), 0.f));
                    if (lane == 63) {
                        out[OUT1 + (b * 128 + o + 0) * S_ + s] = y0;
                        out[OUT1 + (b * 128 + o + 1) * S_ + s] = y1;
                        out[OUT1 + (b * 128 + o + 2) * S_ + s] = y2;
                        out[OUT1 + (b * 128 + o + 3) * S_ + s] = y3;
                    }
                }
            }
            __syncthreads();   // LDS reuse fence before next centroid
        }
    }
}

// ============================================================================
// Fallback sequential path (proven R12 kernels) — used only if ws too small.
// ============================================================================
__global__ __launch_bounds__(FPS_T, 1) void fps_kernel(const float* __restrict__ xyz,
                                                       float* out) {
    const int b = blockIdx.x;
    const int t = threadIdx.x;
    const int lane = t & 63;
    const float* X = xyz + b * 3 * N_;

    v2f px2[FPS_J], py2[FPS_J], pz2[FPS_J], dist2[FPS_J];
#pragma unroll
    for (int j = 0; j < FPS_J; ++j) {
        int n = t + 1024 * j;
        px2[j] = (v2f){X[n], X[n + 512]};
        py2[j] = (v2f){X[N_ + n], X[N_ + n + 512]};
        pz2[j] = (v2f){X[2 * N_ + n], X[2 * N_ + n + 512]};
        dist2[j] = (v2f){1e10f, 1e10f};
    }
    __shared__ u64 pairs[2];
    if (t == 0) { pairs[0] = 0ull; pairs[1] = 0ull; }
    __syncthreads();
    float* oseed = out + OUT2 + b * S_;
    int ci = 0;
    float c0 = X[0], c1 = X[N_], c2 = X[2 * N_];
    for (int step = 0; step < S_; ++step) {
        if (t == 0) oseed[step] = __int_as_float(ci);
        if (t < 3) {
            float cv = (t == 0) ? c0 : (t == 1) ? c1 : c2;
            out[OUT0 + (b * 3 + t) * S_ + step] = cv;
        }
        v2f mv = (v2f){-1.0f, -1.0f};
        {
#pragma clang fp contract(off)
            v2f c0v = (v2f){c0, c0};
            v2f c1v = (v2f){c1, c1};
            v2f c2v = (v2f){c2, c2};
#pragma unroll
            for (int j = 0; j < FPS_J; ++j) {
                v2f e0 = px2[j] - c0v;
                v2f e1 = py2[j] - c1v;
                v2f e2 = pz2[j] - c2v;
                v2f q0 = e0 * e0;
                v2f q1 = e1 * e1;
                v2f q2 = e2 * e2;
                v2f d  = (q0 + q1) + q2;
                v2f dm = __builtin_elementwise_min(dist2[j], d);
                dist2[j] = dm;
                mv = __builtin_elementwise_max(mv, dm);
            }
        }
        float m = fmaxf(mv.x, mv.y);
        float wmax = wave_max_f32(m);
        unsigned mask = 0u;
#pragma unroll
        for (int j = 0; j < FPS_J; ++j) {
            if (dist2[j].x == wmax) mask |= (1u << (2 * j));
            if (dist2[j].y == wmax) mask |= (1u << (2 * j + 1));
        }
        unsigned cand = 0xffffffffu;
        if (mask) {
            int bit = __ffs(mask) - 1;
            cand = (unsigned)(t + (bit << 9));
        }
        unsigned widx = wave_min_u32(cand);
        if (lane == 0) {
            u64 pv = ((u64)(step + 1) << 45) |
                     ((u64)__float_as_uint(wmax) << 13) |
                     (u64)(8191u - widx);
            atomicMax(&pairs[(step + 1) & 1], pv);
        }
        __syncthreads();
        u64 p = pairs[(step + 1) & 1];
        ci = 8191 - (int)(p & 0x1fffull);
        int cu = __builtin_amdgcn_readfirstlane(ci);
        c0 = X[cu];
        c1 = X[N_ + cu];
        c2 = X[2 * N_ + cu];
    }
}

__global__ __launch_bounds__(256) void seedconv_kernel(const int* __restrict__ seed,
                                                       float* out) {
    int t = blockIdx.x * 256 + threadIdx.x;   // 8192
    int b = t >> 10;
    int idx = __float_as_int(out[OUT2 + t]) & 8191;
    out[OUT2 + t] = (float)seed[b * N_ + idx];
}

__global__ __launch_bounds__(256) void ballquery_kernel(const float* __restrict__ xyz,
                                                        float* out) {
    int wid = threadIdx.x >> 6, lane = threadIdx.x & 63;
    int sg = blockIdx.x * 4 + wid;
    int b = sg >> 10, s = sg & 1023;
    const float* X = xyz + b * 3 * N_;
    float c0 = out[OUT0 + (b * 3 + 0) * S_ + s];
    float c1 = out[OUT0 + (b * 3 + 1) * S_ + s];
    float c2 = out[OUT0 + (b * 3 + 2) * S_ + s];
    float* G = out + OUT1 + (b * 128) * S_ + s;
    int cnt = 0, first = 0;
    for (int base = 0; base < N_ && cnt < NS_; base += 128) {
        int n0 = base + lane;
        int n1 = base + 64 + lane;
        float x0 = X[n0], y0 = X[N_ + n0], z0 = X[2 * N_ + n0];
        float x1 = X[n1], y1 = X[N_ + n1], z1 = X[2 * N_ + n1];
        float e0 = x0 - c0, e1 = y0 - c1, e2 = z0 - c2;
        float d0 = fmaf(e2, e2, fmaf(e1, e1, e0 * e0));
        float q0 = x1 - c0, q1 = y1 - c1, q2 = z1 - c2;
        float d1 = fmaf(q2, q2, fmaf(q1, q1, q0 * q0));
        u64 m0b = __ballot(d0 <= 0.04f);
        if (m0b) {
            if (cnt == 0) first = base + __ffsll(m0b) - 1;
            int pos = cnt + (int)__popcll(m0b & ((1ull << lane) - 1ull));
            if ((d0 <= 0.04f) && pos < NS_) G[pos * S_] = __int_as_float(n0);
            cnt += (int)__popcll(m0b);
        }
        u64 m1b = __ballot(d1 <= 0.04f);
        if (m1b) {
            if (cnt == 0) first = base + 64 + __ffsll(m1b) - 1;
            int pos = cnt + (int)__popcll(m1b & ((1ull << lane) - 1ull));
            if ((d1 <= 0.04f) && pos < NS_) G[pos * S_] = __int_as_float(n1);
            cnt += (int)__popcll(m1b);
        }
    }
    if (lane >= cnt && lane < NS_) G[lane * S_] = __int_as_float(first);
}

__global__ __launch_bounds__(256) void mlp_kernel(
    const float* __restrict__ xyz, const float* __restrict__ pts,
    const float* __restrict__ w0, const float* __restrict__ b0,
    const float* __restrict__ g0, const float* __restrict__ be0,
    const float* __restrict__ m0, const float* __restrict__ v0,
    const float* __restrict__ w1, const float* __restrict__ b1,
    const float* __restrict__ g1, const float* __restrict__ be1,
    const float* __restrict__ m1, const float* __restrict__ v1,
    const float* __restrict__ w2, const float* __restrict__ b2,
    const float* __restrict__ g2, const float* __restrict__ be2,
    const float* __restrict__ m2, const float* __restrict__ v2,
    float* out) {
    const int sg = blockIdx.x;
    const int b = sg >> 10, s = sg & 1023;
    const int t = threadIdx.x;
    const int lane = t & 63;
    const int wq = __builtin_amdgcn_readfirstlane(t >> 6);

    __shared__ float f0[64 * 9];
    __shared__ float bufA[64 * 65];
    __shared__ float bufB[64 * 65];
    __shared__ float scs[256], ofs[256];

    {
        float sc, of;
        if (t < 64) {
            int c = t;
            sc = g0[c] / sqrtf(v0[c] + 1e-5f);
            of = (b0[c] - m0[c]) * sc + be0[c];
        } else if (t < 128) {
            int c = t - 64;
            sc = g1[c] / sqrtf(v1[c] + 1e-5f);
            of = (b1[c] - m1[c]) * sc + be1[c];
        } else {
            int c = t - 128;
            sc = g2[c] / sqrtf(v2[c] + 1e-5f);
            of = (b2[c] - m2[c]) * sc + be2[c];
        }
        scs[t] = sc;
        ofs[t] = of;
    }

    if (t < 64) {
        int gidx = __float_as_int(out[OUT1 + (b * 128 + t) * S_ + s]) & 8191;
        const float* X = xyz + b * 3 * N_;
        const float* P = pts + b * 3 * N_;
        float cx = out[OUT0 + (b * 3 + 0) * S_ + s];
        float cy = out[OUT0 + (b * 3 + 1) * S_ + s];
        float cz = out[OUT0 + (b * 3 + 2) * S_ + s];
        f0[t * 9 + 0] = X[gidx] - cx;
        f0[t * 9 + 1] = X[N_ + gidx] - cy;
        f0[t * 9 + 2] = X[2 * N_ + gidx] - cz;
        f0[t * 9 + 3] = P[gidx];
        f0[t * 9 + 4] = P[N_ + gidx];
        f0[t * 9 + 5] = P[2 * N_ + gidx];
    }
    __syncthreads();

    {
        float in[6];
#pragma unroll
        for (int c = 0; c < 6; ++c) in[c] = f0[lane * 9 + c];
#pragma unroll 1
        for (int i = 0; i < 16; i += 4) {
            int o = wq * 16 + i;
            float a0 = 0.f, a1 = 0.f, a2 = 0.f, a3 = 0.f;
#pragma unroll
            for (int c = 0; c < 6; ++c) {
                float rc = in[c];
                a0 = fmaf(rc, w0[(o + 0) * 6 + c], a0);
                a1 = fmaf(rc, w0[(o + 1) * 6 + c], a1);
                a2 = fmaf(rc, w0[(o + 2) * 6 + c], a2);
                a3 = fmaf(rc, w0[(o + 3) * 6 + c], a3);
            }
            bufA[lane * 65 + o + 0] = fmaxf(fmaf(a0, scs[o + 0], ofs[o + 0]), 0.f);
            bufA[lane * 65 + o + 1] = fmaxf(fmaf(a1, scs[o + 1], ofs[o + 1]), 0.f);
            bufA[lane * 65 + o + 2] = fmaxf(fmaf(a2, scs[o + 2], ofs[o + 2]), 0.f);
            bufA[lane * 65 + o + 3] = fmaxf(fmaf(a3, scs[o + 3], ofs[o + 3]), 0.f);
        }
    }
    __syncthreads();

    {
        float r[64];
#pragma unroll
        for (int c = 0; c < 64; ++c) r[c] = bufA[lane * 65 + c];
#pragma unroll 1
        for (int i = 0; i < 16; i += 4) {
            int o = wq * 16 + i;
            float a0 = 0.f, a1 = 0.f, a2 = 0.f, a3 = 0.f;
#pragma unroll
            for (int c = 0; c < 64; ++c) {
                float rc = r[c];
                a0 = fmaf(rc, w1[(o + 0) * 64 + c], a0);
                a1 = fmaf(rc, w1[(o + 1) * 64 + c], a1);
                a2 = fmaf(rc, w1[(o + 2) * 64 + c], a2);
                a3 = fmaf(rc, w1[(o + 3) * 64 + c], a3);
            }
            bufB[lane * 65 + o + 0] = fmaxf(fmaf(a0, scs[64 + o + 0], ofs[64 + o + 0]), 0.f);
            bufB[lane * 65 + o + 1] = fmaxf(fmaf(a1, scs[64 + o + 1], ofs[64 + o + 1]), 0.f);
            bufB[lane * 65 + o + 2] = fmaxf(fmaf(a2, scs[64 + o + 2], ofs[64 + o + 2]), 0.f);
            bufB[lane * 65 + o + 3] = fmaxf(fmaf(a3, scs[64 + o + 3], ofs[64 + o + 3]), 0.f);
        }
    }
    __syncthreads();

    {
        float r[64];
#pragma unroll
        for (int c = 0; c < 64; ++c) r[c] = bufB[lane * 65 + c];
#pragma unroll 1
        for (int i = 0; i < 32; i += 4) {
            int o = wq * 32 + i;
            float a0 = 0.f, a1 = 0.f, a2 = 0.f, a3 = 0.f;
#pragma unroll
            for (int c = 0; c < 64; ++c) {
                float rc = r[c];
                a0 = fmaf(rc, w2[(o + 0) * 64 + c], a0);
                a1 = fmaf(rc, w2[(o + 1) * 64 + c], a1);
                a2 = fmaf(rc, w2[(o + 2) * 64 + c], a2);
                a3 = fmaf(rc, w2[(o + 3) * 64 + c], a3);
            }
            float y0 = wave_max_to_lane63(fmaxf(fmaf(a0, scs[128 + o + 0], ofs[128 + o + 0]), 0.f));
            float y1 = wave_max_to_lane63(fmaxf(fmaf(a1, scs[128 + o + 1], ofs[128 + o + 1]), 0.f));
            float y2 = wave_max_to_lane63(fmaxf(fmaf(a2, scs[128 + o + 2], ofs[128 + o + 2]), 0.f));
            float y3 = wave_max_to_lane63(fmaxf(fmaf(a3, scs[128 + o + 3], ofs[128 + o + 3]), 0.f));
            if (lane == 63) {
                out[OUT1 + (b * 128 + o + 0) * S_ + s] = y0;
                out[OUT1 + (b * 128 + o + 1) * S_ + s] = y1;
                out[OUT1 + (b * 128 + o + 2) * S_ + s] = y2;
                out[OUT1 + (b * 128 + o + 3) * S_ + s] = y3;
            }
        }
    }
}

extern "C" void kernel_launch(void* const* d_in, const int* in_sizes, int n_in,
                              void* d_out, int out_size, void* d_ws, size_t ws_size,
                              hipStream_t stream) {
    const float* xyz  = (const float*)d_in[0];
    const float* pts  = (const float*)d_in[1];
    const int*   seed = (const int*)d_in[2];
    const float* w0 = (const float*)d_in[3];
    const float* b0 = (const float*)d_in[4];
    const float* g0 = (const float*)d_in[5];
    const float* be0 = (const float*)d_in[6];
    const float* m0 = (const float*)d_in[7];
    const float* v0 = (const float*)d_in[8];
    const float* w1 = (const float*)d_in[9];
    const float* b1 = (const float*)d_in[10];
    const float* g1 = (const float*)d_in[11];
    const float* be1 = (const float*)d_in[12];
    const float* m1 = (const float*)d_in[13];
    const float* v1 = (const float*)d_in[14];
    const float* w2 = (const float*)d_in[15];
    const float* b2 = (const float*)d_in[16];
    const float* g2 = (const float*)d_in[17];
    const float* be2 = (const float*)d_in[18];
    const float* m2 = (const float*)d_in[19];
    const float* v2 = (const float*)d_in[20];
    float* out = (float*)d_out;

    if (ws_size >= 1024) {
        int* flags = (int*)d_ws;
        hipMemsetAsync(flags, 0, 1024, stream);
        fused_kernel<<<dim3(256), dim3(512), 0, stream>>>(xyz, pts, seed,
            w0, b0, g0, be0, m0, v0,
            w1, b1, g1, be1, m1, v1,
            w2, b2, g2, be2, m2, v2,
            out, flags);
    } else {
        fps_kernel<<<dim3(B_), dim3(FPS_T), 0, stream>>>(xyz, out);
        seedconv_kernel<<<dim3(8192 / 256), dim3(256), 0, stream>>>(seed, out);
        ballquery_kernel<<<dim3(2048), dim3(256), 0, stream>>>(xyz, out);
        mlp_kernel<<<dim3(8192), dim3(256), 0, stream>>>(xyz, pts,
            w0, b0, g0, be0, m0, v0,
            w1, b1, g1, be1, m1, v1,
            w2, b2, g2, be2, m2, v2,
            out);
    }
}

// Round 15
// 1435.586 us; speedup vs baseline: 1.8383x; 1.5904x over previous
//
#include <hip/hip_runtime.h>

#define B_ 8
#define N_ 8192
#define S_ 1024
#define NS_ 64

typedef float v2f __attribute__((ext_vector_type(2)));
typedef unsigned long long u64;

// out layout (floats) — also used as staging (fully rewritten every launch)
#define OUT0 0                 // new_xyz (B,3,1024)
#define OUT1 24576             // new_points (B,128,1024); rows 0..63 of each
                               //   column hold gi int-bits between kernels 3&4
#define OUT2 1073152           // new_seed (B,1024); holds fps int-bits between
                               //   kernels 1&2

// ---------------------------------------------------------------------------
// DPP 64-lane reductions (row_shr 1/2/4/8, row_bcast 15/31; result lane 63).
// HW-validated on gfx950 in rounds 6-14.
// ---------------------------------------------------------------------------
template <int CTRL>
static __device__ __forceinline__ float dpp_max_step(float v) {
    int o = __builtin_amdgcn_update_dpp(__float_as_int(v), __float_as_int(v),
                                        CTRL, 0xf, 0xf, false);
    return fmaxf(v, __int_as_float(o));
}
static __device__ __forceinline__ float wave_max_to_lane63(float v) {
    v = dpp_max_step<0x111>(v);
    v = dpp_max_step<0x112>(v);
    v = dpp_max_step<0x114>(v);
    v = dpp_max_step<0x118>(v);
    v = dpp_max_step<0x142>(v);
    v = dpp_max_step<0x143>(v);
    return v;                         // valid in lane 63
}
static __device__ __forceinline__ float wave_max_f32(float v) {
    v = wave_max_to_lane63(v);
    return __int_as_float(__builtin_amdgcn_readlane(__float_as_int(v), 63));
}
template <int CTRL>
static __device__ __forceinline__ unsigned dpp_umin_step(unsigned v) {
    unsigned o = (unsigned)__builtin_amdgcn_update_dpp((int)v, (int)v,
                                                       CTRL, 0xf, 0xf, false);
    return v < o ? v : o;
}
static __device__ __forceinline__ unsigned wave_min_u32(unsigned v) {
    v = dpp_umin_step<0x111>(v);
    v = dpp_umin_step<0x112>(v);
    v = dpp_umin_step<0x114>(v);
    v = dpp_umin_step<0x118>(v);
    v = dpp_umin_step<0x142>(v);
    v = dpp_umin_step<0x143>(v);
    return (unsigned)__builtin_amdgcn_readlane((int)v, 63);
}

// ---------------------------------------------------------------------------
// Kernel 1: farthest point sampling — R7/R9/R11 structure (best measured:
// 1078 us, absmax 0.0). One block/batch, 512 threads (8 waves), 16 pts/thread
// as 8 float2. ONE barrier per step:
//   dist update -> DPP wave value-max -> rescan -> DPP wave idx-min
//   -> lane0 atomicMax(u64 pairs[(step+1)&1]) with packed
//   (step+1)<<45 | dist_bits<<13 | (8191-idx)  [step tag monotone => no
//   reset needed] -> barrier -> broadcast pair read -> UNIFORM GLOBAL coord
//   fetch via readfirstlane.
// Negative results (do NOT retry): LDS coord slots (R8/R10, +300-600 ns/step);
// producer/consumer fusion (R13/R14 — worker memory traffic inflates the
// producer's serial-path latency ~2x even at 1 block/CU with t0-only spin).
// ---------------------------------------------------------------------------
#define FPS_T 512
#define FPS_J 8     // float2 per thread (16 points)

__global__ __launch_bounds__(FPS_T, 1) void fps_kernel(const float* __restrict__ xyz,
                                                       float* out) {
    const int b = blockIdx.x;
    const int t = threadIdx.x;          // 0..511
    const int lane = t & 63;
    const float* X = xyz + b * 3 * N_;

    // pair j components: n = t + 1024*j (x), n + 512 (y); bit 2j -> n, 2j+1 -> n+512
    v2f px2[FPS_J], py2[FPS_J], pz2[FPS_J], dist2[FPS_J];
#pragma unroll
    for (int j = 0; j < FPS_J; ++j) {
        int n = t + 1024 * j;
        px2[j] = (v2f){X[n], X[n + 512]};
        py2[j] = (v2f){X[N_ + n], X[N_ + n + 512]};
        pz2[j] = (v2f){X[2 * N_ + n], X[2 * N_ + n + 512]};
        dist2[j] = (v2f){1e10f, 1e10f};
    }

    __shared__ u64 pairs[2];
    if (t == 0) { pairs[0] = 0ull; pairs[1] = 0ull; }
    __syncthreads();

    float* oseed = out + OUT2 + b * S_;

    int ci = 0;
    float c0 = X[0], c1 = X[N_], c2 = X[2 * N_];

    for (int step = 0; step < S_; ++step) {
        if (t == 0) oseed[step] = __int_as_float(ci);

        // packed dist update + value-only max
        v2f mv = (v2f){-1.0f, -1.0f};
        {
#pragma clang fp contract(off)
            v2f c0v = (v2f){c0, c0};
            v2f c1v = (v2f){c1, c1};
            v2f c2v = (v2f){c2, c2};
#pragma unroll
            for (int j = 0; j < FPS_J; ++j) {
                v2f e0 = px2[j] - c0v;
                v2f e1 = py2[j] - c1v;
                v2f e2 = pz2[j] - c2v;
                v2f q0 = e0 * e0;
                v2f q1 = e1 * e1;
                v2f q2 = e2 * e2;
                v2f d  = (q0 + q1) + q2;
                v2f dm = __builtin_elementwise_min(dist2[j], d);
                dist2[j] = dm;
                mv = __builtin_elementwise_max(mv, dm);
            }
        }
        float m = fmaxf(mv.x, mv.y);

        // wave value max
        float wmax = wave_max_f32(m);

        // rescan vs wave max -> this thread's lowest matching point index
        unsigned mask = 0u;
#pragma unroll
        for (int j = 0; j < FPS_J; ++j) {
            if (dist2[j].x == wmax) mask |= (1u << (2 * j));
            if (dist2[j].y == wmax) mask |= (1u << (2 * j + 1));
        }
        unsigned cand = 0xffffffffu;
        if (mask) {
            int bit = __ffs(mask) - 1;
            cand = (unsigned)(t + (bit << 9));   // = point index n
        }
        unsigned widx = wave_min_u32(cand);      // wave's winning point index

        if (lane == 0) {
            u64 pv = ((u64)(step + 1) << 45) |
                     ((u64)__float_as_uint(wmax) << 13) |
                     (u64)(8191u - widx);
            atomicMax(&pairs[(step + 1) & 1], pv);
        }
        __syncthreads();   // the ONE barrier

        u64 p = pairs[(step + 1) & 1];
        ci = 8191 - (int)(p & 0x1fffull);
        int cu = __builtin_amdgcn_readfirstlane(ci);
        c0 = X[cu];
        c1 = X[N_ + cu];
        c2 = X[2 * N_ + cu];
    }
}

// ---------------------------------------------------------------------------
// Kernel 2: read fps int-bits from OUT2, gather centroid coords -> OUT0,
// overwrite OUT2 with the gathered seed value (same-thread read-then-write).
// ---------------------------------------------------------------------------
__global__ __launch_bounds__(256) void gather_kernel(const float* __restrict__ xyz,
                                                     const int* __restrict__ seed,
                                                     float* out) {
    int t = blockIdx.x * 256 + threadIdx.x;   // 8192
    int b = t >> 10, s = t & 1023;
    int idx = __float_as_int(out[OUT2 + t]) & 8191;
    const float* X = xyz + b * 3 * N_;
    float x = X[idx], y = X[N_ + idx], z = X[2 * N_ + idx];
    out[OUT0 + (b * 3 + 0) * S_ + s] = x;
    out[OUT0 + (b * 3 + 1) * S_ + s] = y;
    out[OUT0 + (b * 3 + 2) * S_ + s] = z;
    out[OUT2 + t] = (float)seed[b * N_ + idx];
}

// ---------------------------------------------------------------------------
// Kernel 3: ball query. One wave per centroid; ballot-compaction collects the
// 64 lowest-index in-radius points; pad with first. Direct |p-c|^2 via fma
// (membership feeds only output 1, threshold 163.84 — borderline flips are
// harmless). 2 chunks (128 pts) per iteration for load/ballot overlap.
// ---------------------------------------------------------------------------
__global__ __launch_bounds__(256) void ballquery_kernel(const float* __restrict__ xyz,
                                                        float* out) {
    int wid = threadIdx.x >> 6, lane = threadIdx.x & 63;
    int sg = blockIdx.x * 4 + wid;            // 0..8191 centroid id
    int b = sg >> 10, s = sg & 1023;
    const float* X = xyz + b * 3 * N_;
    float c0 = out[OUT0 + (b * 3 + 0) * S_ + s];
    float c1 = out[OUT0 + (b * 3 + 1) * S_ + s];
    float c2 = out[OUT0 + (b * 3 + 2) * S_ + s];
    float* G = out + OUT1 + (b * 128) * S_ + s;   // column s, rows 0..63, stride S_

    int cnt = 0, first = 0;
    for (int base = 0; base < N_ && cnt < NS_; base += 128) {
        int n0 = base + lane;
        int n1 = base + 64 + lane;
        float x0 = X[n0], y0 = X[N_ + n0], z0 = X[2 * N_ + n0];
        float x1 = X[n1], y1 = X[N_ + n1], z1 = X[2 * N_ + n1];
        float e0 = x0 - c0, e1 = y0 - c1, e2 = z0 - c2;
        float d0 = fmaf(e2, e2, fmaf(e1, e1, e0 * e0));
        float f0 = x1 - c0, f1 = y1 - c1, f2 = z1 - c2;
        float d1 = fmaf(f2, f2, fmaf(f1, f1, f0 * f0));

        u64 mask0 = __ballot(d0 <= 0.04f);
        if (mask0) {
            if (cnt == 0) first = base + __ffsll(mask0) - 1;
            int pos = cnt + (int)__popcll(mask0 & ((1ull << lane) - 1ull));
            if ((d0 <= 0.04f) && pos < NS_) G[pos * S_] = __int_as_float(n0);
            cnt += (int)__popcll(mask0);
        }
        u64 mask1 = __ballot(d1 <= 0.04f);
        if (mask1) {
            if (cnt == 0) first = base + 64 + __ffsll(mask1) - 1;
            int pos = cnt + (int)__popcll(mask1 & ((1ull << lane) - 1ull));
            if ((d1 <= 0.04f) && pos < NS_) G[pos * S_] = __int_as_float(n1);
            cnt += (int)__popcll(mask1);
        }
    }
    if (lane >= cnt && lane < NS_) G[lane * S_] = __int_as_float(first);
}

// ---------------------------------------------------------------------------
// Kernel 4: fused gather + 3-layer pointwise MLP (+BN+ReLU) + max over K.
// One block (256 thr) per centroid; k = lane, wave wq owns an o-slice.
// BN folded into (sc, ofs) LDS tables. o-loops unrolled x4 -> 4 independent
// fmac chains (ILP). k-max via DPP; lane 63 stores.
// ---------------------------------------------------------------------------
__global__ __launch_bounds__(256) void mlp_kernel(
    const float* __restrict__ xyz, const float* __restrict__ pts,
    const float* __restrict__ w0, const float* __restrict__ b0,
    const float* __restrict__ g0, const float* __restrict__ be0,
    const float* __restrict__ m0, const float* __restrict__ v0,
    const float* __restrict__ w1, const float* __restrict__ b1,
    const float* __restrict__ g1, const float* __restrict__ be1,
    const float* __restrict__ m1, const float* __restrict__ v1,
    const float* __restrict__ w2, const float* __restrict__ b2,
    const float* __restrict__ g2, const float* __restrict__ be2,
    const float* __restrict__ m2, const float* __restrict__ v2,
    float* out) {
    const int sg = blockIdx.x;
    const int b = sg >> 10, s = sg & 1023;
    const int t = threadIdx.x;
    const int lane = t & 63;
    const int wq = __builtin_amdgcn_readfirstlane(t >> 6);

    __shared__ float f0[64 * 9];
    __shared__ float bufA[64 * 65];
    __shared__ float bufB[64 * 65];
    __shared__ float scs[256], ofs[256];   // [0,64)=L0 [64,128)=L1 [128,256)=L2

    // per-channel BN fold (one sqrt+div per thread)
    {
        float sc, of;
        if (t < 64) {
            int c = t;
            sc = g0[c] / sqrtf(v0[c] + 1e-5f);
            of = (b0[c] - m0[c]) * sc + be0[c];
        } else if (t < 128) {
            int c = t - 64;
            sc = g1[c] / sqrtf(v1[c] + 1e-5f);
            of = (b1[c] - m1[c]) * sc + be1[c];
        } else {
            int c = t - 128;
            sc = g2[c] / sqrtf(v2[c] + 1e-5f);
            of = (b2[c] - m2[c]) * sc + be2[c];
        }
        scs[t] = sc;
        ofs[t] = of;
    }

    if (t < 64) {
        int gidx = __float_as_int(out[OUT1 + (b * 128 + t) * S_ + s]) & 8191;
        const float* X = xyz + b * 3 * N_;
        const float* P = pts + b * 3 * N_;
        float cx = out[OUT0 + (b * 3 + 0) * S_ + s];
        float cy = out[OUT0 + (b * 3 + 1) * S_ + s];
        float cz = out[OUT0 + (b * 3 + 2) * S_ + s];
        f0[t * 9 + 0] = X[gidx] - cx;
        f0[t * 9 + 1] = X[N_ + gidx] - cy;
        f0[t * 9 + 2] = X[2 * N_ + gidx] - cz;
        f0[t * 9 + 3] = P[gidx];
        f0[t * 9 + 4] = P[N_ + gidx];
        f0[t * 9 + 5] = P[2 * N_ + gidx];
    }
    __syncthreads();

    // layer 0: 6 -> 64  (4 independent acc chains)
    {
        float in[6];
#pragma unroll
        for (int c = 0; c < 6; ++c) in[c] = f0[lane * 9 + c];
#pragma unroll 1
        for (int i = 0; i < 16; i += 4) {
            int o = wq * 16 + i;
            float a0 = 0.f, a1 = 0.f, a2 = 0.f, a3 = 0.f;
#pragma unroll
            for (int c = 0; c < 6; ++c) {
                float rc = in[c];
                a0 = fmaf(rc, w0[(o + 0) * 6 + c], a0);
                a1 = fmaf(rc, w0[(o + 1) * 6 + c], a1);
                a2 = fmaf(rc, w0[(o + 2) * 6 + c], a2);
                a3 = fmaf(rc, w0[(o + 3) * 6 + c], a3);
            }
            bufA[lane * 65 + o + 0] = fmaxf(fmaf(a0, scs[o + 0], ofs[o + 0]), 0.f);
            bufA[lane * 65 + o + 1] = fmaxf(fmaf(a1, scs[o + 1], ofs[o + 1]), 0.f);
            bufA[lane * 65 + o + 2] = fmaxf(fmaf(a2, scs[o + 2], ofs[o + 2]), 0.f);
            bufA[lane * 65 + o + 3] = fmaxf(fmaf(a3, scs[o + 3], ofs[o + 3]), 0.f);
        }
    }
    __syncthreads();

    // layer 1: 64 -> 64  (4 independent acc chains)
    {
        float r[64];
#pragma unroll
        for (int c = 0; c < 64; ++c) r[c] = bufA[lane * 65 + c];
#pragma unroll 1
        for (int i = 0; i < 16; i += 4) {
            int o = wq * 16 + i;
            float a0 = 0.f, a1 = 0.f, a2 = 0.f, a3 = 0.f;
#pragma unroll
            for (int c = 0; c < 64; ++c) {
                float rc = r[c];
                a0 = fmaf(rc, w1[(o + 0) * 64 + c], a0);
                a1 = fmaf(rc, w1[(o + 1) * 64 + c], a1);
                a2 = fmaf(rc, w1[(o + 2) * 64 + c], a2);
                a3 = fmaf(rc, w1[(o + 3) * 64 + c], a3);
            }
            bufB[lane * 65 + o + 0] = fmaxf(fmaf(a0, scs[64 + o + 0], ofs[64 + o + 0]), 0.f);
            bufB[lane * 65 + o + 1] = fmaxf(fmaf(a1, scs[64 + o + 1], ofs[64 + o + 1]), 0.f);
            bufB[lane * 65 + o + 2] = fmaxf(fmaf(a2, scs[64 + o + 2], ofs[64 + o + 2]), 0.f);
            bufB[lane * 65 + o + 3] = fmaxf(fmaf(a3, scs[64 + o + 3], ofs[64 + o + 3]), 0.f);
        }
    }
    __syncthreads();

    // layer 2: 64 -> 128, fused BN+ReLU+max over k (4 chains; DPP reduce)
    {
        float r[64];
#pragma unroll
        for (int c = 0; c < 64; ++c) r[c] = bufB[lane * 65 + c];
#pragma unroll 1
        for (int i = 0; i < 32; i += 4) {
            int o = wq * 32 + i;
            float a0 = 0.f, a1 = 0.f, a2 = 0.f, a3 = 0.f;
#pragma unroll
            for (int c = 0; c < 64; ++c) {
                float rc = r[c];
                a0 = fmaf(rc, w2[(o + 0) * 64 + c], a0);
                a1 = fmaf(rc, w2[(o + 1) * 64 + c], a1);
                a2 = fmaf(rc, w2[(o + 2) * 64 + c], a2);
                a3 = fmaf(rc, w2[(o + 3) * 64 + c], a3);
            }
            float y0 = wave_max_to_lane63(fmaxf(fmaf(a0, scs[128 + o + 0], ofs[128 + o + 0]), 0.f));
            float y1 = wave_max_to_lane63(fmaxf(fmaf(a1, scs[128 + o + 1], ofs[128 + o + 1]), 0.f));
            float y2 = wave_max_to_lane63(fmaxf(fmaf(a2, scs[128 + o + 2], ofs[128 + o + 2]), 0.f));
            float y3 = wave_max_to_lane63(fmaxf(fmaf(a3, scs[128 + o + 3], ofs[128 + o + 3]), 0.f));
            if (lane == 63) {
                out[OUT1 + (b * 128 + o + 0) * S_ + s] = y0;
                out[OUT1 + (b * 128 + o + 1) * S_ + s] = y1;
                out[OUT1 + (b * 128 + o + 2) * S_ + s] = y2;
                out[OUT1 + (b * 128 + o + 3) * S_ + s] = y3;
            }
        }
    }
}

extern "C" void kernel_launch(void* const* d_in, const int* in_sizes, int n_in,
                              void* d_out, int out_size, void* d_ws, size_t ws_size,
                              hipStream_t stream) {
    const float* xyz  = (const float*)d_in[0];
    const float* pts  = (const float*)d_in[1];
    const int*   seed = (const int*)d_in[2];
    const float* w0 = (const float*)d_in[3];
    const float* b0 = (const float*)d_in[4];
    const float* g0 = (const float*)d_in[5];
    const float* be0 = (const float*)d_in[6];
    const float* m0 = (const float*)d_in[7];
    const float* v0 = (const float*)d_in[8];
    const float* w1 = (const float*)d_in[9];
    const float* b1 = (const float*)d_in[10];
    const float* g1 = (const float*)d_in[11];
    const float* be1 = (const float*)d_in[12];
    const float* m1 = (const float*)d_in[13];
    const float* v1 = (const float*)d_in[14];
    const float* w2 = (const float*)d_in[15];
    const float* b2 = (const float*)d_in[16];
    const float* g2 = (const float*)d_in[17];
    const float* be2 = (const float*)d_in[18];
    const float* m2 = (const float*)d_in[19];
    const float* v2 = (const float*)d_in[20];
    float* out = (float*)d_out;
    (void)d_ws; (void)ws_size;   // workspace intentionally unused

    fps_kernel<<<dim3(B_), dim3(FPS_T), 0, stream>>>(xyz, out);
    gather_kernel<<<dim3(8192 / 256), dim3(256), 0, stream>>>(xyz, seed, out);
    ballquery_kernel<<<dim3(2048), dim3(256), 0, stream>>>(xyz, out);
    mlp_kernel<<<dim3(8192), dim3(256), 0, stream>>>(xyz, pts,
        w0, b0, g0, be0, m0, v0,
        w1, b1, g1, be1, m1, v1,
        w2, b2, g2, be2, m2, v2,
        out);
}

// Round 16
// 1380.690 us; speedup vs baseline: 1.9114x; 1.0398x over previous
//
#include <hip/hip_runtime.h>

#define B_ 8
#define N_ 8192
#define S_ 1024
#define NS_ 64

typedef float v2f __attribute__((ext_vector_type(2)));
typedef unsigned long long u64;
typedef short bf16x8 __attribute__((ext_vector_type(8)));
typedef float f32x4 __attribute__((ext_vector_type(4)));

// out layout (floats) — also used as staging (fully rewritten every launch)
#define OUT0 0                 // new_xyz (B,3,1024)
#define OUT1 24576             // new_points (B,128,1024); rows 0..63 of each
                               //   column hold gi int-bits between kernels 3&4
#define OUT2 1073152           // new_seed (B,1024); holds fps int-bits between
                               //   kernels 1&2

// ---------------------------------------------------------------------------
// DPP 64-lane reductions (row_shr 1/2/4/8, row_bcast 15/31; result lane 63).
// HW-validated on gfx950 in rounds 6-15.
// ---------------------------------------------------------------------------
template <int CTRL>
static __device__ __forceinline__ float dpp_max_step(float v) {
    int o = __builtin_amdgcn_update_dpp(__float_as_int(v), __float_as_int(v),
                                        CTRL, 0xf, 0xf, false);
    return fmaxf(v, __int_as_float(o));
}
static __device__ __forceinline__ float wave_max_f32(float v) {
    v = dpp_max_step<0x111>(v);
    v = dpp_max_step<0x112>(v);
    v = dpp_max_step<0x114>(v);
    v = dpp_max_step<0x118>(v);
    v = dpp_max_step<0x142>(v);
    v = dpp_max_step<0x143>(v);
    return __int_as_float(__builtin_amdgcn_readlane(__float_as_int(v), 63));
}
template <int CTRL>
static __device__ __forceinline__ unsigned dpp_umin_step(unsigned v) {
    unsigned o = (unsigned)__builtin_amdgcn_update_dpp((int)v, (int)v,
                                                       CTRL, 0xf, 0xf, false);
    return v < o ? v : o;
}
static __device__ __forceinline__ unsigned wave_min_u32(unsigned v) {
    v = dpp_umin_step<0x111>(v);
    v = dpp_umin_step<0x112>(v);
    v = dpp_umin_step<0x114>(v);
    v = dpp_umin_step<0x118>(v);
    v = dpp_umin_step<0x142>(v);
    v = dpp_umin_step<0x143>(v);
    return (unsigned)__builtin_amdgcn_readlane((int)v, 63);
}

// round-to-nearest-even f32 -> bf16 bits
static __device__ __forceinline__ short f2bf(float f) {
    unsigned u = __float_as_uint(f);
    return (short)((u + 0x7FFFu + ((u >> 16) & 1u)) >> 16);
}

// ---------------------------------------------------------------------------
// Kernel 1: farthest point sampling — R7/R9/R11 structure (best measured:
// 1078 us, absmax 0.0). Negative results (do NOT retry): LDS coord slots
// (R8/R10); producer/consumer fusion (R13/R14 — worker traffic inflates the
// producer's serial path ~2x even at 1 block/CU with t0-only spin).
// ---------------------------------------------------------------------------
#define FPS_T 512
#define FPS_J 8     // float2 per thread (16 points)

__global__ __launch_bounds__(FPS_T, 1) void fps_kernel(const float* __restrict__ xyz,
                                                       float* out) {
    const int b = blockIdx.x;
    const int t = threadIdx.x;          // 0..511
    const int lane = t & 63;
    const float* X = xyz + b * 3 * N_;

    v2f px2[FPS_J], py2[FPS_J], pz2[FPS_J], dist2[FPS_J];
#pragma unroll
    for (int j = 0; j < FPS_J; ++j) {
        int n = t + 1024 * j;
        px2[j] = (v2f){X[n], X[n + 512]};
        py2[j] = (v2f){X[N_ + n], X[N_ + n + 512]};
        pz2[j] = (v2f){X[2 * N_ + n], X[2 * N_ + n + 512]};
        dist2[j] = (v2f){1e10f, 1e10f};
    }

    __shared__ u64 pairs[2];
    if (t == 0) { pairs[0] = 0ull; pairs[1] = 0ull; }
    __syncthreads();

    float* oseed = out + OUT2 + b * S_;

    int ci = 0;
    float c0 = X[0], c1 = X[N_], c2 = X[2 * N_];

    for (int step = 0; step < S_; ++step) {
        if (t == 0) oseed[step] = __int_as_float(ci);

        v2f mv = (v2f){-1.0f, -1.0f};
        {
#pragma clang fp contract(off)
            v2f c0v = (v2f){c0, c0};
            v2f c1v = (v2f){c1, c1};
            v2f c2v = (v2f){c2, c2};
#pragma unroll
            for (int j = 0; j < FPS_J; ++j) {
                v2f e0 = px2[j] - c0v;
                v2f e1 = py2[j] - c1v;
                v2f e2 = pz2[j] - c2v;
                v2f q0 = e0 * e0;
                v2f q1 = e1 * e1;
                v2f q2 = e2 * e2;
                v2f d  = (q0 + q1) + q2;
                v2f dm = __builtin_elementwise_min(dist2[j], d);
                dist2[j] = dm;
                mv = __builtin_elementwise_max(mv, dm);
            }
        }
        float m = fmaxf(mv.x, mv.y);
        float wmax = wave_max_f32(m);

        unsigned mask = 0u;
#pragma unroll
        for (int j = 0; j < FPS_J; ++j) {
            if (dist2[j].x == wmax) mask |= (1u << (2 * j));
            if (dist2[j].y == wmax) mask |= (1u << (2 * j + 1));
        }
        unsigned cand = 0xffffffffu;
        if (mask) {
            int bit = __ffs(mask) - 1;
            cand = (unsigned)(t + (bit << 9));
        }
        unsigned widx = wave_min_u32(cand);

        if (lane == 0) {
            u64 pv = ((u64)(step + 1) << 45) |
                     ((u64)__float_as_uint(wmax) << 13) |
                     (u64)(8191u - widx);
            atomicMax(&pairs[(step + 1) & 1], pv);
        }
        __syncthreads();

        u64 p = pairs[(step + 1) & 1];
        ci = 8191 - (int)(p & 0x1fffull);
        int cu = __builtin_amdgcn_readfirstlane(ci);
        c0 = X[cu];
        c1 = X[N_ + cu];
        c2 = X[2 * N_ + cu];
    }
}

// ---------------------------------------------------------------------------
// Kernel 2: read fps int-bits from OUT2, gather centroid coords -> OUT0,
// overwrite OUT2 with the gathered seed value (same-thread read-then-write).
// ---------------------------------------------------------------------------
__global__ __launch_bounds__(256) void gather_kernel(const float* __restrict__ xyz,
                                                     const int* __restrict__ seed,
                                                     float* out) {
    int t = blockIdx.x * 256 + threadIdx.x;   // 8192
    int b = t >> 10, s = t & 1023;
    int idx = __float_as_int(out[OUT2 + t]) & 8191;
    const float* X = xyz + b * 3 * N_;
    float x = X[idx], y = X[N_ + idx], z = X[2 * N_ + idx];
    out[OUT0 + (b * 3 + 0) * S_ + s] = x;
    out[OUT0 + (b * 3 + 1) * S_ + s] = y;
    out[OUT0 + (b * 3 + 2) * S_ + s] = z;
    out[OUT2 + t] = (float)seed[b * N_ + idx];
}

// ---------------------------------------------------------------------------
// Kernel 3: ball query (unchanged from R12/R15).
// ---------------------------------------------------------------------------
__global__ __launch_bounds__(256) void ballquery_kernel(const float* __restrict__ xyz,
                                                        float* out) {
    int wid = threadIdx.x >> 6, lane = threadIdx.x & 63;
    int sg = blockIdx.x * 4 + wid;            // 0..8191 centroid id
    int b = sg >> 10, s = sg & 1023;
    const float* X = xyz + b * 3 * N_;
    float c0 = out[OUT0 + (b * 3 + 0) * S_ + s];
    float c1 = out[OUT0 + (b * 3 + 1) * S_ + s];
    float c2 = out[OUT0 + (b * 3 + 2) * S_ + s];
    float* G = out + OUT1 + (b * 128) * S_ + s;

    int cnt = 0, first = 0;
    for (int base = 0; base < N_ && cnt < NS_; base += 128) {
        int n0 = base + lane;
        int n1 = base + 64 + lane;
        float x0 = X[n0], y0 = X[N_ + n0], z0 = X[2 * N_ + n0];
        float x1 = X[n1], y1 = X[N_ + n1], z1 = X[2 * N_ + n1];
        float e0 = x0 - c0, e1 = y0 - c1, e2 = z0 - c2;
        float d0 = fmaf(e2, e2, fmaf(e1, e1, e0 * e0));
        float f0 = x1 - c0, f1 = y1 - c1, f2 = z1 - c2;
        float d1 = fmaf(f2, f2, fmaf(f1, f1, f0 * f0));

        u64 mask0 = __ballot(d0 <= 0.04f);
        if (mask0) {
            if (cnt == 0) first = base + __ffsll(mask0) - 1;
            int pos = cnt + (int)__popcll(mask0 & ((1ull << lane) - 1ull));
            if ((d0 <= 0.04f) && pos < NS_) G[pos * S_] = __int_as_float(n0);
            cnt += (int)__popcll(mask0);
        }
        u64 mask1 = __ballot(d1 <= 0.04f);
        if (mask1) {
            if (cnt == 0) first = base + 64 + __ffsll(mask1) - 1;
            int pos = cnt + (int)__popcll(mask1 & ((1ull << lane) - 1ull));
            if ((d1 <= 0.04f) && pos < NS_) G[pos * S_] = __int_as_float(n1);
            cnt += (int)__popcll(mask1);
        }
    }
    if (lane >= cnt && lane < NS_) G[lane * S_] = __int_as_float(first);
}

// ---------------------------------------------------------------------------
// Kernel 4: MFMA mlp. One block (256 thr, 4 waves) per centroid.
// L0 (K=6) on VALU -> featA bf16 LDS [64 pts][72-stride ch]. Layers 1/2 on
// mfma_f32_16x16x32_bf16: wave w owns m-tile rows [16w,16w+16); A-frag
// A[m=lane&15][k=quad*8+j] via 16B-aligned ds_read_b128 (stride 72*2=144 B);
// B-frag from global w1/w2 (L1-resident) + RNE cvt: lane n=lane&15 reads
// row (nt*16+n), k = ks*32+quad*8..+7. C/D: col(n)=lane&15, row(m)=quad*4+reg
// [m89-verified]. L2 epilogue: BN+ReLU, 4-reg max, shfl_xor 16/32, cross-wave
// LDS stage, 128 threads final max + store. bf16 error O(0.3) << 163.84.
// ---------------------------------------------------------------------------
__global__ __launch_bounds__(256) void mlp_kernel(
    const float* __restrict__ xyz, const float* __restrict__ pts,
    const float* __restrict__ w0, const float* __restrict__ b0,
    const float* __restrict__ g0, const float* __restrict__ be0,
    const float* __restrict__ m0, const float* __restrict__ v0,
    const float* __restrict__ w1, const float* __restrict__ b1,
    const float* __restrict__ g1, const float* __restrict__ be1,
    const float* __restrict__ m1, const float* __restrict__ v1,
    const float* __restrict__ w2, const float* __restrict__ b2,
    const float* __restrict__ g2, const float* __restrict__ be2,
    const float* __restrict__ m2, const float* __restrict__ v2,
    float* out) {
    const int sg = blockIdx.x;
    const int b = sg >> 10, s = sg & 1023;
    const int t = threadIdx.x;
    const int lane = t & 63;
    const int wq = __builtin_amdgcn_readfirstlane(t >> 6);   // 0..3
    const int ln = lane & 15;
    const int quad = (lane >> 4) & 3;

    __shared__ float f0[64 * 9];
    __shared__ short featA[64 * 72];
    __shared__ short featB[64 * 72];
    __shared__ float wmaxs[4 * 132];
    __shared__ float scs[256], ofs[256];   // [0,64)=L0 [64,128)=L1 [128,256)=L2

    // per-channel BN fold (one sqrt+div per thread)
    {
        float sc, of;
        if (t < 64) {
            int c = t;
            sc = g0[c] / sqrtf(v0[c] + 1e-5f);
            of = (b0[c] - m0[c]) * sc + be0[c];
        } else if (t < 128) {
            int c = t - 64;
            sc = g1[c] / sqrtf(v1[c] + 1e-5f);
            of = (b1[c] - m1[c]) * sc + be1[c];
        } else {
            int c = t - 128;
            sc = g2[c] / sqrtf(v2[c] + 1e-5f);
            of = (b2[c] - m2[c]) * sc + be2[c];
        }
        scs[t] = sc;
        ofs[t] = of;
    }

    if (t < 64) {
        int gidx = __float_as_int(out[OUT1 + (b * 128 + t) * S_ + s]) & 8191;
        const float* X = xyz + b * 3 * N_;
        const float* P = pts + b * 3 * N_;
        float cx = out[OUT0 + (b * 3 + 0) * S_ + s];
        float cy = out[OUT0 + (b * 3 + 1) * S_ + s];
        float cz = out[OUT0 + (b * 3 + 2) * S_ + s];
        f0[t * 9 + 0] = X[gidx] - cx;
        f0[t * 9 + 1] = X[N_ + gidx] - cy;
        f0[t * 9 + 2] = X[2 * N_ + gidx] - cz;
        f0[t * 9 + 3] = P[gidx];
        f0[t * 9 + 4] = P[N_ + gidx];
        f0[t * 9 + 5] = P[2 * N_ + gidx];
    }
    __syncthreads();

    // layer 0: 6 -> 64 on VALU; point = lane, wave owns 16-channel o-slice;
    // writes featA bf16 [point][channel]
    {
        float in[6];
#pragma unroll
        for (int c = 0; c < 6; ++c) in[c] = f0[lane * 9 + c];
#pragma unroll 1
        for (int i = 0; i < 16; i += 4) {
            int o = wq * 16 + i;
            float a0 = 0.f, a1 = 0.f, a2 = 0.f, a3 = 0.f;
#pragma unroll
            for (int c = 0; c < 6; ++c) {
                float rc = in[c];
                a0 = fmaf(rc, w0[(o + 0) * 6 + c], a0);
                a1 = fmaf(rc, w0[(o + 1) * 6 + c], a1);
                a2 = fmaf(rc, w0[(o + 2) * 6 + c], a2);
                a3 = fmaf(rc, w0[(o + 3) * 6 + c], a3);
            }
            featA[lane * 72 + o + 0] = f2bf(fmaxf(fmaf(a0, scs[o + 0], ofs[o + 0]), 0.f));
            featA[lane * 72 + o + 1] = f2bf(fmaxf(fmaf(a1, scs[o + 1], ofs[o + 1]), 0.f));
            featA[lane * 72 + o + 2] = f2bf(fmaxf(fmaf(a2, scs[o + 2], ofs[o + 2]), 0.f));
            featA[lane * 72 + o + 3] = f2bf(fmaxf(fmaf(a3, scs[o + 3], ofs[o + 3]), 0.f));
        }
    }
    __syncthreads();

    const int arow = 16 * wq + ln;   // this wave's m-tile row for A-frags

    // layer 1: 64 -> 64 via MFMA (4 ntiles x 2 ksteps)
    {
        bf16x8 a1f[2];
#pragma unroll
        for (int ks = 0; ks < 2; ++ks)
            a1f[ks] = *(const bf16x8*)&featA[arow * 72 + ks * 32 + quad * 8];

#pragma unroll
        for (int nt = 0; nt < 4; ++nt) {
            f32x4 acc = {0.f, 0.f, 0.f, 0.f};
#pragma unroll
            for (int ks = 0; ks < 2; ++ks) {
                const float* wr = w1 + (nt * 16 + ln) * 64 + ks * 32 + quad * 8;
                float4 p = *(const float4*)wr;
                float4 q = *(const float4*)(wr + 4);
                bf16x8 bf = {f2bf(p.x), f2bf(p.y), f2bf(p.z), f2bf(p.w),
                             f2bf(q.x), f2bf(q.y), f2bf(q.z), f2bf(q.w)};
                acc = __builtin_amdgcn_mfma_f32_16x16x32_bf16(a1f[ks], bf, acc, 0, 0, 0);
            }
            int o = nt * 16 + ln;
            float sc = scs[64 + o], of = ofs[64 + o];
#pragma unroll
            for (int reg = 0; reg < 4; ++reg) {
                float y = fmaxf(fmaf(acc[reg], sc, of), 0.f);
                featB[(16 * wq + quad * 4 + reg) * 72 + o] = f2bf(y);
            }
        }
    }
    // no barrier needed: each wave reads back only its own m-tile rows

    // layer 2: 64 -> 128 via MFMA (8 ntiles x 2 ksteps) + fused k-max
    {
        bf16x8 a2f[2];
#pragma unroll
        for (int ks = 0; ks < 2; ++ks)
            a2f[ks] = *(const bf16x8*)&featB[arow * 72 + ks * 32 + quad * 8];

#pragma unroll
        for (int nt = 0; nt < 8; ++nt) {
            f32x4 acc = {0.f, 0.f, 0.f, 0.f};
#pragma unroll
            for (int ks = 0; ks < 2; ++ks) {
                const float* wr = w2 + (nt * 16 + ln) * 64 + ks * 32 + quad * 8;
                float4 p = *(const float4*)wr;
                float4 q = *(const float4*)(wr + 4);
                bf16x8 bf = {f2bf(p.x), f2bf(p.y), f2bf(p.z), f2bf(p.w),
                             f2bf(q.x), f2bf(q.y), f2bf(q.z), f2bf(q.w)};
                acc = __builtin_amdgcn_mfma_f32_16x16x32_bf16(a2f[ks], bf, acc, 0, 0, 0);
            }
            int o = nt * 16 + ln;
            float sc = scs[128 + o], of = ofs[128 + o];
            float m = -1.f;
#pragma unroll
            for (int reg = 0; reg < 4; ++reg) {
                float y = fmaxf(fmaf(acc[reg], sc, of), 0.f);
                m = fmaxf(m, y);
            }
            // max over the wave's 16 rows: rows live across quads (same ln)
            m = fmaxf(m, __shfl_xor(m, 16, 64));
            m = fmaxf(m, __shfl_xor(m, 32, 64));
            if (lane < 16) wmaxs[wq * 132 + o] = m;
        }
    }
    __syncthreads();

    // final: max over the 4 waves' m-tiles, store new_points
    if (t < 128) {
        float m = fmaxf(fmaxf(wmaxs[0 * 132 + t], wmaxs[1 * 132 + t]),
                        fmaxf(wmaxs[2 * 132 + t], wmaxs[3 * 132 + t]));
        out[OUT1 + (b * 128 + t) * S_ + s] = m;
    }
}

extern "C" void kernel_launch(void* const* d_in, const int* in_sizes, int n_in,
                              void* d_out, int out_size, void* d_ws, size_t ws_size,
                              hipStream_t stream) {
    const float* xyz  = (const float*)d_in[0];
    const float* pts  = (const float*)d_in[1];
    const int*   seed = (const int*)d_in[2];
    const float* w0 = (const float*)d_in[3];
    const float* b0 = (const float*)d_in[4];
    const float* g0 = (const float*)d_in[5];
    const float* be0 = (const float*)d_in[6];
    const float* m0 = (const float*)d_in[7];
    const float* v0 = (const float*)d_in[8];
    const float* w1 = (const float*)d_in[9];
    const float* b1 = (const float*)d_in[10];
    const float* g1 = (const float*)d_in[11];
    const float* be1 = (const float*)d_in[12];
    const float* m1 = (const float*)d_in[13];
    const float* v1 = (const float*)d_in[14];
    const float* w2 = (const float*)d_in[15];
    const float* b2 = (const float*)d_in[16];
    const float* g2 = (const float*)d_in[17];
    const float* be2 = (const float*)d_in[18];
    const float* m2 = (const float*)d_in[19];
    const float* v2 = (const float*)d_in[20];
    float* out = (float*)d_out;
    (void)d_ws; (void)ws_size;   // workspace intentionally unused

    fps_kernel<<<dim3(B_), dim3(FPS_T), 0, stream>>>(xyz, out);
    gather_kernel<<<dim3(8192 / 256), dim3(256), 0, stream>>>(xyz, seed, out);
    ballquery_kernel<<<dim3(2048), dim3(256), 0, stream>>>(xyz, out);
    mlp_kernel<<<dim3(8192), dim3(256), 0, stream>>>(xyz, pts,
        w0, b0, g0, be0, m0, v0,
        w1, b1, g1, be1, m1, v1,
        w2, b2, g2, be2, m2, v2,
        out);
}

// Round 17
// 1376.328 us; speedup vs baseline: 1.9175x; 1.0032x over previous
//
#include <hip/hip_runtime.h>

#define B_ 8
#define N_ 8192
#define S_ 1024
#define NS_ 64

typedef float v2f __attribute__((ext_vector_type(2)));
typedef unsigned long long u64;
typedef short bf16x8 __attribute__((ext_vector_type(8)));
typedef float f32x4 __attribute__((ext_vector_type(4)));

// out layout (floats)
#define OUT0 0                 // new_xyz (B,3,1024)
#define OUT1 24576             // new_points (B,128,1024)
#define OUT2 1073152           // new_seed (B,1024); fps int-bits until down_kernel converts

// ---------------------------------------------------------------------------
// DPP 64-lane reductions (row_shr 1/2/4/8, row_bcast 15/31; result lane 63).
// HW-validated on gfx950 in rounds 6-16.
// ---------------------------------------------------------------------------
template <int CTRL>
static __device__ __forceinline__ float dpp_max_step(float v) {
    int o = __builtin_amdgcn_update_dpp(__float_as_int(v), __float_as_int(v),
                                        CTRL, 0xf, 0xf, false);
    return fmaxf(v, __int_as_float(o));
}
static __device__ __forceinline__ float wave_max_f32(float v) {
    v = dpp_max_step<0x111>(v);
    v = dpp_max_step<0x112>(v);
    v = dpp_max_step<0x114>(v);
    v = dpp_max_step<0x118>(v);
    v = dpp_max_step<0x142>(v);
    v = dpp_max_step<0x143>(v);
    return __int_as_float(__builtin_amdgcn_readlane(__float_as_int(v), 63));
}
template <int CTRL>
static __device__ __forceinline__ unsigned dpp_umin_step(unsigned v) {
    unsigned o = (unsigned)__builtin_amdgcn_update_dpp((int)v, (int)v,
                                                       CTRL, 0xf, 0xf, false);
    return v < o ? v : o;
}
static __device__ __forceinline__ unsigned wave_min_u32(unsigned v) {
    v = dpp_umin_step<0x111>(v);
    v = dpp_umin_step<0x112>(v);
    v = dpp_umin_step<0x114>(v);
    v = dpp_umin_step<0x118>(v);
    v = dpp_umin_step<0x142>(v);
    v = dpp_umin_step<0x143>(v);
    return (unsigned)__builtin_amdgcn_readlane((int)v, 63);
}

// round-to-nearest-even f32 -> bf16 bits
static __device__ __forceinline__ short f2bf(float f) {
    unsigned u = __float_as_uint(f);
    return (short)((u + 0x7FFFu + ((u >> 16) & 1u)) >> 16);
}

// ---------------------------------------------------------------------------
// Kernel 1: farthest point sampling — R7/R9/R11 structure (best measured:
// 1074 us, absmax 0.0). Negative results (do NOT retry): LDS coord slots
// (R8/R10); CONCURRENT producer/consumer fusion (R13/R14 — worker traffic
// inflates the producer's serial path ~2x even at 1 block/CU, t0-only spin).
// ---------------------------------------------------------------------------
#define FPS_T 512
#define FPS_J 8     // float2 per thread (16 points)

__global__ __launch_bounds__(FPS_T, 1) void fps_kernel(const float* __restrict__ xyz,
                                                       float* out) {
    const int b = blockIdx.x;
    const int t = threadIdx.x;          // 0..511
    const int lane = t & 63;
    const float* X = xyz + b * 3 * N_;

    v2f px2[FPS_J], py2[FPS_J], pz2[FPS_J], dist2[FPS_J];
#pragma unroll
    for (int j = 0; j < FPS_J; ++j) {
        int n = t + 1024 * j;
        px2[j] = (v2f){X[n], X[n + 512]};
        py2[j] = (v2f){X[N_ + n], X[N_ + n + 512]};
        pz2[j] = (v2f){X[2 * N_ + n], X[2 * N_ + n + 512]};
        dist2[j] = (v2f){1e10f, 1e10f};
    }

    __shared__ u64 pairs[2];
    if (t == 0) { pairs[0] = 0ull; pairs[1] = 0ull; }
    __syncthreads();

    float* oseed = out + OUT2 + b * S_;

    int ci = 0;
    float c0 = X[0], c1 = X[N_], c2 = X[2 * N_];

    for (int step = 0; step < S_; ++step) {
        if (t == 0) oseed[step] = __int_as_float(ci);

        v2f mv = (v2f){-1.0f, -1.0f};
        {
#pragma clang fp contract(off)
            v2f c0v = (v2f){c0, c0};
            v2f c1v = (v2f){c1, c1};
            v2f c2v = (v2f){c2, c2};
#pragma unroll
            for (int j = 0; j < FPS_J; ++j) {
                v2f e0 = px2[j] - c0v;
                v2f e1 = py2[j] - c1v;
                v2f e2 = pz2[j] - c2v;
                v2f q0 = e0 * e0;
                v2f q1 = e1 * e1;
                v2f q2 = e2 * e2;
                v2f d  = (q0 + q1) + q2;
                v2f dm = __builtin_elementwise_min(dist2[j], d);
                dist2[j] = dm;
                mv = __builtin_elementwise_max(mv, dm);
            }
        }
        float m = fmaxf(mv.x, mv.y);
        float wmax = wave_max_f32(m);

        unsigned mask = 0u;
#pragma unroll
        for (int j = 0; j < FPS_J; ++j) {
            if (dist2[j].x == wmax) mask |= (1u << (2 * j));
            if (dist2[j].y == wmax) mask |= (1u << (2 * j + 1));
        }
        unsigned cand = 0xffffffffu;
        if (mask) {
            int bit = __ffs(mask) - 1;
            cand = (unsigned)(t + (bit << 9));
        }
        unsigned widx = wave_min_u32(cand);

        if (lane == 0) {
            u64 pv = ((u64)(step + 1) << 45) |
                     ((u64)__float_as_uint(wmax) << 13) |
                     (u64)(8191u - widx);
            atomicMax(&pairs[(step + 1) & 1], pv);
        }
        __syncthreads();

        u64 p = pairs[(step + 1) & 1];
        ci = 8191 - (int)(p & 0x1fffull);
        int cu = __builtin_amdgcn_readfirstlane(ci);
        c0 = X[cu];
        c1 = X[N_ + cu];
        c2 = X[2 * N_ + cu];
    }
}

// ---------------------------------------------------------------------------
// Kernel 2: fused downstream — one block (256 thr, 4 waves) per centroid:
//   (a) read fps idx bits from OUT2 (broadcast), write new_xyz + new_seed
//   (b) 4-wave ball query: wave w scans its quarter [2048w, 2048w+2048);
//       per-wave ascending candidate lists over disjoint ascending ranges
//       concatenate into the globally-lowest-64 (reference sort semantics);
//       pad with overall-first
//   (c) R16 MFMA mlp: L0 VALU -> bf16 LDS; L1/L2 mfma_f32_16x16x32_bf16
//       (A-frag m120-verified, C/D m89-verified); fused BN+ReLU+k-max.
// ---------------------------------------------------------------------------
__global__ __launch_bounds__(256) void down_kernel(
    const float* __restrict__ xyz, const float* __restrict__ pts,
    const int* __restrict__ seed,
    const float* __restrict__ w0, const float* __restrict__ b0,
    const float* __restrict__ g0, const float* __restrict__ be0,
    const float* __restrict__ m0, const float* __restrict__ v0,
    const float* __restrict__ w1, const float* __restrict__ b1,
    const float* __restrict__ g1, const float* __restrict__ be1,
    const float* __restrict__ m1, const float* __restrict__ v1,
    const float* __restrict__ w2, const float* __restrict__ b2,
    const float* __restrict__ g2, const float* __restrict__ be2,
    const float* __restrict__ m2, const float* __restrict__ v2,
    float* out) {
    const int sg = blockIdx.x;
    const int b = sg >> 10, s = sg & 1023;
    const int t = threadIdx.x;
    const int lane = t & 63;
    const int wq = __builtin_amdgcn_readfirstlane(t >> 6);   // 0..3
    const int ln = lane & 15;
    const int quad = (lane >> 4) & 3;

    __shared__ float f0[64 * 9];
    __shared__ short featA[64 * 72];
    __shared__ short featB[64 * 72];
    __shared__ float wmaxs[4 * 132];
    __shared__ float scs[256], ofs[256];
    __shared__ int cand[4 * 64];
    __shared__ int cnts[4];
    __shared__ int gis[64];

    const float* X = xyz + b * 3 * N_;

    // (a) broadcast read of fps index; centroid coords
    int ci = __float_as_int(out[OUT2 + sg]) & 8191;
    float cx = X[ci], cy = X[N_ + ci], cz = X[2 * N_ + ci];

    // per-channel BN fold (one sqrt+div per thread)
    {
        float sc, of;
        if (t < 64) {
            int c = t;
            sc = g0[c] / sqrtf(v0[c] + 1e-5f);
            of = (b0[c] - m0[c]) * sc + be0[c];
        } else if (t < 128) {
            int c = t - 64;
            sc = g1[c] / sqrtf(v1[c] + 1e-5f);
            of = (b1[c] - m1[c]) * sc + be1[c];
        } else {
            int c = t - 128;
            sc = g2[c] / sqrtf(v2[c] + 1e-5f);
            of = (b2[c] - m2[c]) * sc + be2[c];
        }
        scs[t] = sc;
        ofs[t] = of;
    }
    __syncthreads();   // all OUT2 reads complete (vmcnt drained) before overwrite

    if (t == 0) {
        out[OUT0 + (b * 3 + 0) * S_ + s] = cx;
        out[OUT0 + (b * 3 + 1) * S_ + s] = cy;
        out[OUT0 + (b * 3 + 2) * S_ + s] = cz;
        out[OUT2 + sg] = (float)seed[b * N_ + ci];
    }

    // (b) 4-wave ball query: wave wq scans [2048*wq, 2048*wq+2048)
    {
        int cnt = 0;
        const int wbase = wq << 11;
        for (int base = 0; base < 2048 && cnt < NS_; base += 128) {
            int n0 = wbase + base + lane;
            int n1 = n0 + 64;
            float x0 = X[n0], y0 = X[N_ + n0], z0 = X[2 * N_ + n0];
            float x1 = X[n1], y1 = X[N_ + n1], z1 = X[2 * N_ + n1];
            float e0 = x0 - cx, e1 = y0 - cy, e2 = z0 - cz;
            float d0 = fmaf(e2, e2, fmaf(e1, e1, e0 * e0));
            float q0 = x1 - cx, q1 = y1 - cy, q2 = z1 - cz;
            float d1 = fmaf(q2, q2, fmaf(q1, q1, q0 * q0));

            u64 mask0 = __ballot(d0 <= 0.04f);
            if (mask0) {
                int pos = cnt + (int)__popcll(mask0 & ((1ull << lane) - 1ull));
                if ((d0 <= 0.04f) && pos < NS_) cand[(wq << 6) + pos] = n0;
                cnt += (int)__popcll(mask0);
            }
            u64 mask1 = __ballot(d1 <= 0.04f);
            if (mask1) {
                int pos = cnt + (int)__popcll(mask1 & ((1ull << lane) - 1ull));
                if ((d1 <= 0.04f) && pos < NS_) cand[(wq << 6) + pos] = n1;
                cnt += (int)__popcll(mask1);
            }
        }
        if (lane == 0) cnts[wq] = cnt;
    }
    __syncthreads();

    // merge: first 64 in global ascending index order; pad with overall-first
    if (t < 64) {
        int k = t;
        int start = 0, sel = -1, firstv = -1;
#pragma unroll
        for (int w = 0; w < 4; ++w) {
            int cw = min(cnts[w], NS_);
            if (firstv < 0 && cw > 0) firstv = cand[(w << 6)];
            if (sel < 0 && k < start + cw) sel = cand[(w << 6) + (k - start)];
            start += cw;
        }
        if (sel < 0) sel = firstv;
        gis[t] = sel;
    }
    __syncthreads();

    if (t < 64) {
        int gidx = gis[t] & 8191;
        const float* P = pts + b * 3 * N_;
        f0[t * 9 + 0] = X[gidx] - cx;
        f0[t * 9 + 1] = X[N_ + gidx] - cy;
        f0[t * 9 + 2] = X[2 * N_ + gidx] - cz;
        f0[t * 9 + 3] = P[gidx];
        f0[t * 9 + 4] = P[N_ + gidx];
        f0[t * 9 + 5] = P[2 * N_ + gidx];
    }
    __syncthreads();

    // (c) layer 0: 6 -> 64 on VALU; point = lane, wave owns 16-channel slice
    {
        float in[6];
#pragma unroll
        for (int c = 0; c < 6; ++c) in[c] = f0[lane * 9 + c];
#pragma unroll 1
        for (int i = 0; i < 16; i += 4) {
            int o = wq * 16 + i;
            float a0 = 0.f, a1 = 0.f, a2 = 0.f, a3 = 0.f;
#pragma unroll
            for (int c = 0; c < 6; ++c) {
                float rc = in[c];
                a0 = fmaf(rc, w0[(o + 0) * 6 + c], a0);
                a1 = fmaf(rc, w0[(o + 1) * 6 + c], a1);
                a2 = fmaf(rc, w0[(o + 2) * 6 + c], a2);
                a3 = fmaf(rc, w0[(o + 3) * 6 + c], a3);
            }
            featA[lane * 72 + o + 0] = f2bf(fmaxf(fmaf(a0, scs[o + 0], ofs[o + 0]), 0.f));
            featA[lane * 72 + o + 1] = f2bf(fmaxf(fmaf(a1, scs[o + 1], ofs[o + 1]), 0.f));
            featA[lane * 72 + o + 2] = f2bf(fmaxf(fmaf(a2, scs[o + 2], ofs[o + 2]), 0.f));
            featA[lane * 72 + o + 3] = f2bf(fmaxf(fmaf(a3, scs[o + 3], ofs[o + 3]), 0.f));
        }
    }
    __syncthreads();

    const int arow = 16 * wq + ln;   // this wave's m-tile row for A-frags

    // layer 1: 64 -> 64 via MFMA (4 ntiles x 2 ksteps)
    {
        bf16x8 a1f[2];
#pragma unroll
        for (int ks = 0; ks < 2; ++ks)
            a1f[ks] = *(const bf16x8*)&featA[arow * 72 + ks * 32 + quad * 8];

#pragma unroll
        for (int nt = 0; nt < 4; ++nt) {
            f32x4 acc = {0.f, 0.f, 0.f, 0.f};
#pragma unroll
            for (int ks = 0; ks < 2; ++ks) {
                const float* wr = w1 + (nt * 16 + ln) * 64 + ks * 32 + quad * 8;
                float4 p = *(const float4*)wr;
                float4 q = *(const float4*)(wr + 4);
                bf16x8 bf = {f2bf(p.x), f2bf(p.y), f2bf(p.z), f2bf(p.w),
                             f2bf(q.x), f2bf(q.y), f2bf(q.z), f2bf(q.w)};
                acc = __builtin_amdgcn_mfma_f32_16x16x32_bf16(a1f[ks], bf, acc, 0, 0, 0);
            }
            int o = nt * 16 + ln;
            float sc = scs[64 + o], of = ofs[64 + o];
#pragma unroll
            for (int reg = 0; reg < 4; ++reg) {
                float y = fmaxf(fmaf(acc[reg], sc, of), 0.f);
                featB[(16 * wq + quad * 4 + reg) * 72 + o] = f2bf(y);
            }
        }
    }
    // no barrier: each wave reads back only its own m-tile rows

    // layer 2: 64 -> 128 via MFMA (8 ntiles x 2 ksteps) + fused k-max
    {
        bf16x8 a2f[2];
#pragma unroll
        for (int ks = 0; ks < 2; ++ks)
            a2f[ks] = *(const bf16x8*)&featB[arow * 72 + ks * 32 + quad * 8];

#pragma unroll
        for (int nt = 0; nt < 8; ++nt) {
            f32x4 acc = {0.f, 0.f, 0.f, 0.f};
#pragma unroll
            for (int ks = 0; ks < 2; ++ks) {
                const float* wr = w2 + (nt * 16 + ln) * 64 + ks * 32 + quad * 8;
                float4 p = *(const float4*)wr;
                float4 q = *(const float4*)(wr + 4);
                bf16x8 bf = {f2bf(p.x), f2bf(p.y), f2bf(p.z), f2bf(p.w),
                             f2bf(q.x), f2bf(q.y), f2bf(q.z), f2bf(q.w)};
                acc = __builtin_amdgcn_mfma_f32_16x16x32_bf16(a2f[ks], bf, acc, 0, 0, 0);
            }
            int o = nt * 16 + ln;
            float sc = scs[128 + o], of = ofs[128 + o];
            float m = -1.f;
#pragma unroll
            for (int reg = 0; reg < 4; ++reg) {
                float y = fmaxf(fmaf(acc[reg], sc, of), 0.f);
                m = fmaxf(m, y);
            }
            m = fmaxf(m, __shfl_xor(m, 16, 64));
            m = fmaxf(m, __shfl_xor(m, 32, 64));
            if (lane < 16) wmaxs[wq * 132 + o] = m;
        }
    }
    __syncthreads();

    // final: max over the 4 waves' m-tiles, store new_points
    if (t < 128) {
        float m = fmaxf(fmaxf(wmaxs[0 * 132 + t], wmaxs[1 * 132 + t]),
                        fmaxf(wmaxs[2 * 132 + t], wmaxs[3 * 132 + t]));
        out[OUT1 + (b * 128 + t) * S_ + s] = m;
    }
}

extern "C" void kernel_launch(void* const* d_in, const int* in_sizes, int n_in,
                              void* d_out, int out_size, void* d_ws, size_t ws_size,
                              hipStream_t stream) {
    const float* xyz  = (const float*)d_in[0];
    const float* pts  = (const float*)d_in[1];
    const int*   seed = (const int*)d_in[2];
    const float* w0 = (const float*)d_in[3];
    const float* b0 = (const float*)d_in[4];
    const float* g0 = (const float*)d_in[5];
    const float* be0 = (const float*)d_in[6];
    const float* m0 = (const float*)d_in[7];
    const float* v0 = (const float*)d_in[8];
    const float* w1 = (const float*)d_in[9];
    const float* b1 = (const float*)d_in[10];
    const float* g1 = (const float*)d_in[11];
    const float* be1 = (const float*)d_in[12];
    const float* m1 = (const float*)d_in[13];
    const float* v1 = (const float*)d_in[14];
    const float* w2 = (const float*)d_in[15];
    const float* b2 = (const float*)d_in[16];
    const float* g2 = (const float*)d_in[17];
    const float* be2 = (const float*)d_in[18];
    const float* m2 = (const float*)d_in[19];
    const float* v2 = (const float*)d_in[20];
    float* out = (float*)d_out;
    (void)d_ws; (void)ws_size;   // workspace intentionally unused

    fps_kernel<<<dim3(B_), dim3(FPS_T), 0, stream>>>(xyz, out);
    down_kernel<<<dim3(B_ * S_), dim3(256), 0, stream>>>(xyz, pts, seed,
        w0, b0, g0, be0, m0, v0,
        w1, b1, g1, be1, m1, v1,
        w2, b2, g2, be2, m2, v2,
        out);
}

// Round 18
// 1291.606 us; speedup vs baseline: 2.0432x; 1.0656x over previous
//
#include <hip/hip_runtime.h>

#define B_ 8
#define N_ 8192
#define S_ 1024
#define NS_ 64

typedef float v2f __attribute__((ext_vector_type(2)));
typedef unsigned long long u64;
typedef short bf16x8 __attribute__((ext_vector_type(8)));
typedef float f32x4 __attribute__((ext_vector_type(4)));

// out layout (floats)
#define OUT0 0                 // new_xyz (B,3,1024)
#define OUT1 24576             // new_points (B,128,1024)
#define OUT2 1073152           // new_seed (B,1024); fps int-bits until down_kernel converts

// ---------------------------------------------------------------------------
// DPP 64-lane reductions (row_shr 1/2/4/8, row_bcast 15/31; result lane 63).
// HW-validated on gfx950 in rounds 6-17.
// ---------------------------------------------------------------------------
template <int CTRL>
static __device__ __forceinline__ float dpp_max_step(float v) {
    int o = __builtin_amdgcn_update_dpp(__float_as_int(v), __float_as_int(v),
                                        CTRL, 0xf, 0xf, false);
    return fmaxf(v, __int_as_float(o));
}
static __device__ __forceinline__ float wave_max_f32(float v) {
    v = dpp_max_step<0x111>(v);
    v = dpp_max_step<0x112>(v);
    v = dpp_max_step<0x114>(v);
    v = dpp_max_step<0x118>(v);
    v = dpp_max_step<0x142>(v);
    v = dpp_max_step<0x143>(v);
    return __int_as_float(__builtin_amdgcn_readlane(__float_as_int(v), 63));
}
template <int CTRL>
static __device__ __forceinline__ unsigned dpp_umin_step(unsigned v) {
    unsigned o = (unsigned)__builtin_amdgcn_update_dpp((int)v, (int)v,
                                                       CTRL, 0xf, 0xf, false);
    return v < o ? v : o;
}
static __device__ __forceinline__ unsigned wave_min_u32(unsigned v) {
    v = dpp_umin_step<0x111>(v);
    v = dpp_umin_step<0x112>(v);
    v = dpp_umin_step<0x114>(v);
    v = dpp_umin_step<0x118>(v);
    v = dpp_umin_step<0x142>(v);
    v = dpp_umin_step<0x143>(v);
    return (unsigned)__builtin_amdgcn_readlane((int)v, 63);
}

// round-to-nearest-even f32 -> bf16 bits
static __device__ __forceinline__ short f2bf(float f) {
    unsigned u = __float_as_uint(f);
    return (short)((u + 0x7FFFu + ((u >> 16) & 1u)) >> 16);
}

// ---------------------------------------------------------------------------
// Kernel 1: farthest point sampling — R7/R9/R11 structure (best measured:
// 1074 us, absmax 0.0). Negative results (do NOT retry): LDS coord slots
// (R8/R10); CONCURRENT producer/consumer fusion (R13/R14 — worker traffic
// inflates the producer's serial path ~2x even at 1 block/CU, t0-only spin).
// ---------------------------------------------------------------------------
#define FPS_T 512
#define FPS_J 8     // float2 per thread (16 points)

__global__ __launch_bounds__(FPS_T, 1) void fps_kernel(const float* __restrict__ xyz,
                                                       float* out) {
    const int b = blockIdx.x;
    const int t = threadIdx.x;          // 0..511
    const int lane = t & 63;
    const float* X = xyz + b * 3 * N_;

    v2f px2[FPS_J], py2[FPS_J], pz2[FPS_J], dist2[FPS_J];
#pragma unroll
    for (int j = 0; j < FPS_J; ++j) {
        int n = t + 1024 * j;
        px2[j] = (v2f){X[n], X[n + 512]};
        py2[j] = (v2f){X[N_ + n], X[N_ + n + 512]};
        pz2[j] = (v2f){X[2 * N_ + n], X[2 * N_ + n + 512]};
        dist2[j] = (v2f){1e10f, 1e10f};
    }

    __shared__ u64 pairs[2];
    if (t == 0) { pairs[0] = 0ull; pairs[1] = 0ull; }
    __syncthreads();

    float* oseed = out + OUT2 + b * S_;

    int ci = 0;
    float c0 = X[0], c1 = X[N_], c2 = X[2 * N_];

    for (int step = 0; step < S_; ++step) {
        if (t == 0) oseed[step] = __int_as_float(ci);

        v2f mv = (v2f){-1.0f, -1.0f};
        {
#pragma clang fp contract(off)
            v2f c0v = (v2f){c0, c0};
            v2f c1v = (v2f){c1, c1};
            v2f c2v = (v2f){c2, c2};
#pragma unroll
            for (int j = 0; j < FPS_J; ++j) {
                v2f e0 = px2[j] - c0v;
                v2f e1 = py2[j] - c1v;
                v2f e2 = pz2[j] - c2v;
                v2f q0 = e0 * e0;
                v2f q1 = e1 * e1;
                v2f q2 = e2 * e2;
                v2f d  = (q0 + q1) + q2;
                v2f dm = __builtin_elementwise_min(dist2[j], d);
                dist2[j] = dm;
                mv = __builtin_elementwise_max(mv, dm);
            }
        }
        float m = fmaxf(mv.x, mv.y);
        float wmax = wave_max_f32(m);

        unsigned mask = 0u;
#pragma unroll
        for (int j = 0; j < FPS_J; ++j) {
            if (dist2[j].x == wmax) mask |= (1u << (2 * j));
            if (dist2[j].y == wmax) mask |= (1u << (2 * j + 1));
        }
        unsigned cand = 0xffffffffu;
        if (mask) {
            int bit = __ffs(mask) - 1;
            cand = (unsigned)(t + (bit << 9));
        }
        unsigned widx = wave_min_u32(cand);

        if (lane == 0) {
            u64 pv = ((u64)(step + 1) << 45) |
                     ((u64)__float_as_uint(wmax) << 13) |
                     (u64)(8191u - widx);
            atomicMax(&pairs[(step + 1) & 1], pv);
        }
        __syncthreads();

        u64 p = pairs[(step + 1) & 1];
        ci = 8191 - (int)(p & 0x1fffull);
        int cu = __builtin_amdgcn_readfirstlane(ci);
        c0 = X[cu];
        c1 = X[N_ + cu];
        c2 = X[2 * N_ + cu];
    }
}

// ---------------------------------------------------------------------------
// Kernel 1b: one-shot weight conversion w1 (64x64) + w2 (128x64) -> bf16 in
// d_ws. Shared by all 8192 down_kernel blocks (saves ~192 f2bf x 4 VALU inst
// per lane per block and halves weight load bytes).
// ---------------------------------------------------------------------------
__global__ __launch_bounds__(256) void wconv_kernel(const float* __restrict__ w1,
                                                    const float* __restrict__ w2,
                                                    short* __restrict__ wbf) {
    int t = blockIdx.x * 256 + threadIdx.x;   // 0..12287
    float v = (t < 4096) ? w1[t] : w2[t - 4096];
    wbf[t] = f2bf(v);
}

// ---------------------------------------------------------------------------
// Kernel 2: fused downstream — one block (256 thr, 4 waves) per centroid:
//   (a) read fps idx bits from OUT2 (broadcast), write new_xyz + new_seed
//   (b) 4-wave ball query, FIXED 16-iteration loop (no early exit: a 2048-pt
//       quarter holds ~2 ball members, exit never fired; fixed trip count
//       lets the compiler pipeline loads across iterations)
//   (c) MFMA mlp (R16-verified layouts); weights from pre-converted bf16
//       d_ws when available (wbf != nullptr), else inline f2bf fallback.
// ---------------------------------------------------------------------------
__global__ __launch_bounds__(256) void down_kernel(
    const float* __restrict__ xyz, const float* __restrict__ pts,
    const int* __restrict__ seed,
    const float* __restrict__ w0, const float* __restrict__ b0,
    const float* __restrict__ g0, const float* __restrict__ be0,
    const float* __restrict__ m0, const float* __restrict__ v0,
    const float* __restrict__ w1, const float* __restrict__ b1,
    const float* __restrict__ g1, const float* __restrict__ be1,
    const float* __restrict__ m1, const float* __restrict__ v1,
    const float* __restrict__ w2, const float* __restrict__ b2,
    const float* __restrict__ g2, const float* __restrict__ be2,
    const float* __restrict__ m2, const float* __restrict__ v2,
    float* out, const short* __restrict__ wbf) {
    const int sg = blockIdx.x;
    const int b = sg >> 10, s = sg & 1023;
    const int t = threadIdx.x;
    const int lane = t & 63;
    const int wq = __builtin_amdgcn_readfirstlane(t >> 6);   // 0..3
    const int ln = lane & 15;
    const int quad = (lane >> 4) & 3;

    __shared__ float f0[64 * 9];
    __shared__ short featA[64 * 72];
    __shared__ short featB[64 * 72];
    __shared__ float wmaxs[4 * 132];
    __shared__ float scs[256], ofs[256];
    __shared__ int cand[4 * 64];
    __shared__ int cnts[4];
    __shared__ int gis[64];

    const float* X = xyz + b * 3 * N_;

    // (a) broadcast read of fps index; centroid coords
    int ci = __float_as_int(out[OUT2 + sg]) & 8191;
    float cx = X[ci], cy = X[N_ + ci], cz = X[2 * N_ + ci];

    // per-channel BN fold (one sqrt+div per thread)
    {
        float sc, of;
        if (t < 64) {
            int c = t;
            sc = g0[c] / sqrtf(v0[c] + 1e-5f);
            of = (b0[c] - m0[c]) * sc + be0[c];
        } else if (t < 128) {
            int c = t - 64;
            sc = g1[c] / sqrtf(v1[c] + 1e-5f);
            of = (b1[c] - m1[c]) * sc + be1[c];
        } else {
            int c = t - 128;
            sc = g2[c] / sqrtf(v2[c] + 1e-5f);
            of = (b2[c] - m2[c]) * sc + be2[c];
        }
        scs[t] = sc;
        ofs[t] = of;
    }
    __syncthreads();   // all OUT2 reads complete (vmcnt drained) before overwrite

    if (t == 0) {
        out[OUT0 + (b * 3 + 0) * S_ + s] = cx;
        out[OUT0 + (b * 3 + 1) * S_ + s] = cy;
        out[OUT0 + (b * 3 + 2) * S_ + s] = cz;
        out[OUT2 + sg] = (float)seed[b * N_ + ci];
    }

    // (b) 4-wave ball query: wave wq scans [2048*wq, 2048*wq+2048), 16 iters
    {
        int cnt = 0;
        const int wbase = wq << 11;
#pragma unroll 2
        for (int base = 0; base < 2048; base += 128) {
            int n0 = wbase + base + lane;
            int n1 = n0 + 64;
            float x0 = X[n0], y0 = X[N_ + n0], z0 = X[2 * N_ + n0];
            float x1 = X[n1], y1 = X[N_ + n1], z1 = X[2 * N_ + n1];
            float e0 = x0 - cx, e1 = y0 - cy, e2 = z0 - cz;
            float d0 = fmaf(e2, e2, fmaf(e1, e1, e0 * e0));
            float q0 = x1 - cx, q1 = y1 - cy, q2 = z1 - cz;
            float d1 = fmaf(q2, q2, fmaf(q1, q1, q0 * q0));

            u64 mask0 = __ballot(d0 <= 0.04f);
            if (mask0) {
                int pos = cnt + (int)__popcll(mask0 & ((1ull << lane) - 1ull));
                if ((d0 <= 0.04f) && pos < NS_) cand[(wq << 6) + pos] = n0;
                cnt += (int)__popcll(mask0);
            }
            u64 mask1 = __ballot(d1 <= 0.04f);
            if (mask1) {
                int pos = cnt + (int)__popcll(mask1 & ((1ull << lane) - 1ull));
                if ((d1 <= 0.04f) && pos < NS_) cand[(wq << 6) + pos] = n1;
                cnt += (int)__popcll(mask1);
            }
        }
        if (lane == 0) cnts[wq] = cnt;
    }
    __syncthreads();

    // merge: first 64 in global ascending index order; pad with overall-first
    if (t < 64) {
        int k = t;
        int start = 0, sel = -1, firstv = -1;
#pragma unroll
        for (int w = 0; w < 4; ++w) {
            int cw = min(cnts[w], NS_);
            if (firstv < 0 && cw > 0) firstv = cand[(w << 6)];
            if (sel < 0 && k < start + cw) sel = cand[(w << 6) + (k - start)];
            start += cw;
        }
        if (sel < 0) sel = firstv;
        gis[t] = sel;
    }
    __syncthreads();

    if (t < 64) {
        int gidx = gis[t] & 8191;
        const float* P = pts + b * 3 * N_;
        f0[t * 9 + 0] = X[gidx] - cx;
        f0[t * 9 + 1] = X[N_ + gidx] - cy;
        f0[t * 9 + 2] = X[2 * N_ + gidx] - cz;
        f0[t * 9 + 3] = P[gidx];
        f0[t * 9 + 4] = P[N_ + gidx];
        f0[t * 9 + 5] = P[2 * N_ + gidx];
    }
    __syncthreads();

    // (c) layer 0: 6 -> 64 on VALU; point = lane, wave owns 16-channel slice
    {
        float in[6];
#pragma unroll
        for (int c = 0; c < 6; ++c) in[c] = f0[lane * 9 + c];
#pragma unroll 1
        for (int i = 0; i < 16; i += 4) {
            int o = wq * 16 + i;
            float a0 = 0.f, a1 = 0.f, a2 = 0.f, a3 = 0.f;
#pragma unroll
            for (int c = 0; c < 6; ++c) {
                float rc = in[c];
                a0 = fmaf(rc, w0[(o + 0) * 6 + c], a0);
                a1 = fmaf(rc, w0[(o + 1) * 6 + c], a1);
                a2 = fmaf(rc, w0[(o + 2) * 6 + c], a2);
                a3 = fmaf(rc, w0[(o + 3) * 6 + c], a3);
            }
            featA[lane * 72 + o + 0] = f2bf(fmaxf(fmaf(a0, scs[o + 0], ofs[o + 0]), 0.f));
            featA[lane * 72 + o + 1] = f2bf(fmaxf(fmaf(a1, scs[o + 1], ofs[o + 1]), 0.f));
            featA[lane * 72 + o + 2] = f2bf(fmaxf(fmaf(a2, scs[o + 2], ofs[o + 2]), 0.f));
            featA[lane * 72 + o + 3] = f2bf(fmaxf(fmaf(a3, scs[o + 3], ofs[o + 3]), 0.f));
        }
    }
    __syncthreads();

    const int arow = 16 * wq + ln;   // this wave's m-tile row for A-frags
    const bool usebf = (wbf != nullptr);

    // layer 1: 64 -> 64 via MFMA (4 ntiles x 2 ksteps)
    {
        bf16x8 a1f[2];
#pragma unroll
        for (int ks = 0; ks < 2; ++ks)
            a1f[ks] = *(const bf16x8*)&featA[arow * 72 + ks * 32 + quad * 8];

#pragma unroll
        for (int nt = 0; nt < 4; ++nt) {
            f32x4 acc = {0.f, 0.f, 0.f, 0.f};
#pragma unroll
            for (int ks = 0; ks < 2; ++ks) {
                int off = (nt * 16 + ln) * 64 + ks * 32 + quad * 8;
                bf16x8 bf;
                if (usebf) {
                    bf = *(const bf16x8*)&wbf[off];
                } else {
                    const float* wr = w1 + off;
                    float4 p = *(const float4*)wr;
                    float4 q = *(const float4*)(wr + 4);
                    bf = (bf16x8){f2bf(p.x), f2bf(p.y), f2bf(p.z), f2bf(p.w),
                                  f2bf(q.x), f2bf(q.y), f2bf(q.z), f2bf(q.w)};
                }
                acc = __builtin_amdgcn_mfma_f32_16x16x32_bf16(a1f[ks], bf, acc, 0, 0, 0);
            }
            int o = nt * 16 + ln;
            float sc = scs[64 + o], of = ofs[64 + o];
#pragma unroll
            for (int reg = 0; reg < 4; ++reg) {
                float y = fmaxf(fmaf(acc[reg], sc, of), 0.f);
                featB[(16 * wq + quad * 4 + reg) * 72 + o] = f2bf(y);
            }
        }
    }
    // no barrier: each wave reads back only its own m-tile rows

    // layer 2: 64 -> 128 via MFMA (8 ntiles x 2 ksteps) + fused k-max
    {
        bf16x8 a2f[2];
#pragma unroll
        for (int ks = 0; ks < 2; ++ks)
            a2f[ks] = *(const bf16x8*)&featB[arow * 72 + ks * 32 + quad * 8];

#pragma unroll
        for (int nt = 0; nt < 8; ++nt) {
            f32x4 acc = {0.f, 0.f, 0.f, 0.f};
#pragma unroll
            for (int ks = 0; ks < 2; ++ks) {
                int off = (nt * 16 + ln) * 64 + ks * 32 + quad * 8;
                bf16x8 bf;
                if (usebf) {
                    bf = *(const bf16x8*)&wbf[4096 + off];
                } else {
                    const float* wr = w2 + off;
                    float4 p = *(const float4*)wr;
                    float4 q = *(const float4*)(wr + 4);
                    bf = (bf16x8){f2bf(p.x), f2bf(p.y), f2bf(p.z), f2bf(p.w),
                                  f2bf(q.x), f2bf(q.y), f2bf(q.z), f2bf(q.w)};
                }
                acc = __builtin_amdgcn_mfma_f32_16x16x32_bf16(a2f[ks], bf, acc, 0, 0, 0);
            }
            int o = nt * 16 + ln;
            float sc = scs[128 + o], of = ofs[128 + o];
            float m = -1.f;
#pragma unroll
            for (int reg = 0; reg < 4; ++reg) {
                float y = fmaxf(fmaf(acc[reg], sc, of), 0.f);
                m = fmaxf(m, y);
            }
            m = fmaxf(m, __shfl_xor(m, 16, 64));
            m = fmaxf(m, __shfl_xor(m, 32, 64));
            if (lane < 16) wmaxs[wq * 132 + o] = m;
        }
    }
    __syncthreads();

    // final: max over the 4 waves' m-tiles, store new_points
    if (t < 128) {
        float m = fmaxf(fmaxf(wmaxs[0 * 132 + t], wmaxs[1 * 132 + t]),
                        fmaxf(wmaxs[2 * 132 + t], wmaxs[3 * 132 + t]));
        out[OUT1 + (b * 128 + t) * S_ + s] = m;
    }
}

extern "C" void kernel_launch(void* const* d_in, const int* in_sizes, int n_in,
                              void* d_out, int out_size, void* d_ws, size_t ws_size,
                              hipStream_t stream) {
    const float* xyz  = (const float*)d_in[0];
    const float* pts  = (const float*)d_in[1];
    const int*   seed = (const int*)d_in[2];
    const float* w0 = (const float*)d_in[3];
    const float* b0 = (const float*)d_in[4];
    const float* g0 = (const float*)d_in[5];
    const float* be0 = (const float*)d_in[6];
    const float* m0 = (const float*)d_in[7];
    const float* v0 = (const float*)d_in[8];
    const float* w1 = (const float*)d_in[9];
    const float* b1 = (const float*)d_in[10];
    const float* g1 = (const float*)d_in[11];
    const float* be1 = (const float*)d_in[12];
    const float* m1 = (const float*)d_in[13];
    const float* v1 = (const float*)d_in[14];
    const float* w2 = (const float*)d_in[15];
    const float* b2 = (const float*)d_in[16];
    const float* g2 = (const float*)d_in[17];
    const float* be2 = (const float*)d_in[18];
    const float* m2 = (const float*)d_in[19];
    const float* v2 = (const float*)d_in[20];
    float* out = (float*)d_out;

    short* wbf = nullptr;
    if (ws_size >= 12288 * sizeof(short)) {
        wbf = (short*)d_ws;
        wconv_kernel<<<dim3(48), dim3(256), 0, stream>>>(w1, w2, wbf);
    }

    fps_kernel<<<dim3(B_), dim3(FPS_T), 0, stream>>>(xyz, out);
    down_kernel<<<dim3(B_ * S_), dim3(256), 0, stream>>>(xyz, pts, seed,
        w0, b0, g0, be0, m0, v0,
        w1, b1, g1, be1, m1, v1,
        w2, b2, g2, be2, m2, v2,
        out, wbf);
}